// Round 17
// baseline (281.317 us; speedup 1.0000x reference)
//
#include <hip/hip_runtime.h>
#include <math.h>

#define B_ 2
#define H_ 48
#define W_ 48
#define C_ 96
#define D_ 192
#define L_ 2304   // H_*W_
#define K_ 4
#define NS 32     // D_STATE
#define RK 6      // DT_RANK
#define CD 70     // RK + 2*NS

#define NC 32         // scan chunks (R16: 16 -> 32 for scan TLP)
#define CL (L_/NC)    // 72 steps per chunk
#define NCH (B_*K_*D_)// 1536 chains

// workspace offsets (floats)
#define BDL (B_*D_*L_)                    // 884736
#define OFF_Z      0                      // z stored (b, l, d)
#define OFF_XPRE   (OFF_Z    + BDL)
#define OFF_XHW    (OFF_XPRE + BDL)
#define OFF_XWH    (OFF_XHW  + BDL)
#define OFF_DELTA  (OFF_XWH  + BDL)      // size B*K*D*L, layout (b,k,d,l)
#define OFF_BS     (OFF_DELTA+ B_*K_*D_*L_)  // (b,k,l,n)
#define OFF_CS     (OFF_BS   + B_*K_*L_*NS)
#define OFF_YS     (OFF_CS   + B_*K_*L_*NS)  // blocked: [bk][c][dg][lc][32]
#define OFF_YF     (OFF_YS   + B_*K_*L_*D_)

// DU aliases the YS region: du layout [bk][c][d(192)][lc(CL)].
#define OFF_DU     OFF_YS

// H0: NCH*NC*NS = 1.57M floats, layout [c][chain][n], SPLIT across two dead
// regions: chunks 0..15 in YF (786432 <= 884736), chunks 16..31 in XPRE
// (XPRE is dead after k2; k3/k4/k56 read only XHW/XWH/Z).
__device__ __forceinline__ size_t h0_off(int cc, int chain, int n) {
    size_t base = (cc < 16) ? ((size_t)OFF_YF   + (size_t)cc*(NCH*NS))
                            : ((size_t)OFF_XPRE + (size_t)(cc-16)*(NCH*NS));
    return base + (size_t)chain*NS + n;
}

// raw v_exp_f32 (exp2); log2e folded into the per-lane A constant once.
__device__ __forceinline__ float fexp2(float x) {
    float r; asm("v_exp_f32 %0, %1" : "=v"(r) : "v"(x)); return r;
}

// ---------------- K1: in_proj GEMM ------------------------------------------
// grid 576 = b(2) * ltile32(72) * es(4); es 0,1 -> xpre (b,d,pos); 2,3 -> z (b,l,d)
__global__ __launch_bounds__(256) void k1_inproj(const float* __restrict__ x,
        const float* __restrict__ w, float* __restrict__ ws) {
    __shared__ __align__(16) float Xs[24*128];   // [cq][l*4+sub], 32 l
    int blk = blockIdx.x;
    int b = blk / 288;
    int rem = blk % 288;
    int l0 = (rem >> 2) * 32;
    int es = rem & 3;
    int tid = threadIdx.x;
    const float4* xs4 = (const float4*)(x + (size_t)(b*L_ + l0)*C_);
    #pragma unroll
    for (int it = 0; it < 3; ++it) {
        int i4 = it*256 + tid;        // 768 float4 = 3072 floats
        float4 v = xs4[i4];
        int idx4 = i4*4;
        int p = idx4 / 96, c = idx4 % 96;   // c % 4 == 0
        *(float4*)&Xs[(c>>2)*128 + p*4] = v;
    }
    __syncthreads();
    int l = tid & 31, eg = tid >> 5;
    int pos = l0 + l;
    float acc[12];
    #pragma unroll
    for (int i = 0; i < 12; ++i) acc[i] = 0.f;
    const float4* wp[12];
    #pragma unroll
    for (int i = 0; i < 12; ++i) {
        int e = es*96 + eg*12 + i;
        wp[i] = (const float4*)(w + (size_t)e*96);
    }
    for (int q = 0; q < 24; ++q) {
        float4 xr = *(const float4*)&Xs[q*128 + l*4];
        #pragma unroll
        for (int i = 0; i < 12; ++i) {
            float4 wv = wp[i][q];
            acc[i] += xr.x*wv.x + xr.y*wv.y + xr.z*wv.z + xr.w*wv.w;
        }
    }
    if (es < 2) {
        float* xpre = ws + OFF_XPRE;
        #pragma unroll
        for (int i = 0; i < 12; ++i) {
            int e = es*96 + eg*12 + i;
            xpre[(size_t)(b*D_ + e)*L_ + pos] = acc[i];
        }
    } else {
        float* zp = ws + OFF_Z + (size_t)(b*L_ + pos)*D_ + (es-2)*96 + eg*12;
        #pragma unroll
        for (int q = 0; q < 3; ++q)
            *(float4*)&zp[q*4] = make_float4(acc[q*4], acc[q*4+1], acc[q*4+2], acc[q*4+3]);
    }
}

// ---------------- K2: depthwise 3x3 conv + SiLU, half-image blocks ----------
__global__ __launch_bounds__(256) void k2_conv(const float* __restrict__ cw,
        const float* __restrict__ cb, float* __restrict__ ws) {
    __shared__ float img[26*48];
    __shared__ float res[24*49];     // padded for transpose read
    int blk = blockIdx.x;            // 768 = bd*2 + half
    int bd = blk >> 1;
    int half = blk & 1;
    int d = bd % D_;
    int hh0 = half * 24;
    int tid = threadIdx.x;
    const float* xp = ws + OFF_XPRE + (size_t)bd*L_;
    for (int it = 0; it < 5; ++it) {
        int idx = it*256 + tid;
        if (idx < 26*48) {
            int gr = hh0 - 1 + idx/48;
            img[idx] = (gr >= 0 && gr < H_) ? xp[gr*48 + idx%48] : 0.f;
        }
    }
    float wr[9];
    #pragma unroll
    for (int j = 0; j < 9; ++j) wr[j] = cw[d*9 + j];
    float bias = cb[d];
    __syncthreads();
    float* hw = ws + OFF_XHW + (size_t)bd*L_ + hh0*48;
    for (int it = 0; it < 5; ++it) {
        int idx = it*256 + tid;
        if (idx < 24*48) {
            int r = idx/48, w0 = idx%48;
            float acc = bias;
            #pragma unroll
            for (int kh = 0; kh < 3; ++kh) {
                #pragma unroll
                for (int kw = 0; kw < 3; ++kw) {
                    int iw = w0 + kw - 1;
                    if (iw >= 0 && iw < W_)
                        acc = fmaf(img[(r+kh)*48 + iw], wr[kh*3 + kw], acc);
                }
            }
            float v = acc / (1.f + __expf(-acc));
            hw[idx] = v;
            res[r*49 + w0] = v;
        }
    }
    __syncthreads();
    float* wh = ws + OFF_XWH + (size_t)bd*L_;
    for (int it = 0; it < 5; ++it) {
        int idx = it*256 + tid;
        if (idx < 24*48) {
            int w0 = idx/24, r = idx%24;
            wh[w0*48 + hh0 + r] = res[r*49 + w0];
        }
    }
}

// ---------------- K3: x_proj matvec + dt_proj + softplus + B/C + du ---------
// grid 1152 = b(2) * k(4) * ltile16(144)
__global__ __launch_bounds__(256) void k3_xproj(const float* __restrict__ xpw,
        const float* __restrict__ dtw, const float* __restrict__ dtb,
        float* __restrict__ ws) {
    __shared__ __align__(16) float Xs[48*64];    // [dq][l*4+sub], 16 l
    __shared__ float xd[CD*17];                  // [c][l], pad 17
    int blk = blockIdx.x;
    int b = blk / 576;
    int rem = blk % 576;
    int k = rem / 144;
    int l0 = (rem % 144) * 16;
    int tid = threadIdx.x;
    const float* src = ws + ((k & 1) ? OFF_XWH : OFF_XHW);
    bool flip = (k >= 2);
    #pragma unroll
    for (int it = 0; it < 12; ++it) {
        int idx = it*256 + tid;
        int d = idx >> 4, l = idx & 15;
        int pos = flip ? (L_ - 1 - (l0 + l)) : (l0 + l);
        Xs[(d>>2)*64 + l*4 + (d&3)] = src[(size_t)(b*D_ + d)*L_ + pos];
    }
    __syncthreads();
    int l = tid & 15, cg = tid >> 4;    // 16 l x 16 cg
    {
        float acc[5] = {0.f, 0.f, 0.f, 0.f, 0.f};
        const float4* wp[5];
        #pragma unroll
        for (int i = 0; i < 5; ++i) {
            int c = cg + 16*i;
            if (c >= CD) c = 0;          // guard OOB; result masked on write
            wp[i] = (const float4*)(xpw + ((size_t)k*CD + c)*D_);
        }
        for (int q = 0; q < 48; ++q) {
            float4 xr = *(const float4*)&Xs[q*64 + l*4];
            #pragma unroll
            for (int i = 0; i < 5; ++i) {
                float4 wv = wp[i][q];
                acc[i] += xr.x*wv.x + xr.y*wv.y + xr.z*wv.z + xr.w*wv.w;
            }
        }
        #pragma unroll
        for (int i = 0; i < 5; ++i) {
            int c = cg + 16*i;
            if (c < CD) xd[c*17 + l] = acc[i];
        }
    }
    __syncthreads();
    {   // dt_proj + softplus -> deltas (b,k,d,l) AND du (blocked scan layout)
        float r[6];
        #pragma unroll
        for (int rr = 0; rr < 6; ++rr) r[rr] = xd[rr*17 + l];
        int bk = b*K_ + k;
        float* dout = ws + OFF_DELTA + (size_t)bk*D_*L_;
        int gl = l0 + l;                 // per-thread: tile may straddle CL=72
        int cch = gl / CL;
        int lc  = gl - cch*CL;
        float* dup = ws + OFF_DU + ((size_t)(bk*NC + cch))*D_*CL;
        int dg = tid >> 4;
        for (int i = 0; i < 12; ++i) {
            int d = dg*12 + i;
            const float* wdt = dtw + ((size_t)k*D_ + d)*6;
            float acc = dtb[k*D_ + d];
            #pragma unroll
            for (int rr = 0; rr < 6; ++rr) acc = fmaf(r[rr], wdt[rr], acc);
            float sp = fmaxf(acc, 0.f) + log1pf(__expf(-fabsf(acc)));
            dout[(size_t)d*L_ + l0 + l] = sp;
            float uv = Xs[(d>>2)*64 + l*4 + (d&3)];   // u in scan order
            dup[(size_t)d*CL + lc] = sp * uv;
        }
    }
    {   // Bs/Cs -> (b,k,l,n)
        float* Bsp = ws + OFF_BS + ((size_t)(b*K_ + k)*L_ + l0)*NS;
        float* Csp = ws + OFF_CS + ((size_t)(b*K_ + k)*L_ + l0)*NS;
        int n = tid & 31, lq = tid >> 5;
        #pragma unroll
        for (int j = 0; j < 2; ++j) {
            int ll = lq + 8*j;
            Bsp[(size_t)ll*NS + n] = xd[(RK + n)*17 + ll];
            Csp[(size_t)ll*NS + n] = xd[(RK + NS + n)*17 + ll];
        }
    }
}

// ---------------- K4a: local chunk scan + in-LDS combine -> H0 --------------
// block = (bk, d-pair); 1024 threads = 32 chunks x 32 states; 2 chains/lane.
// Double-buffered register prefetch (R14 mechanism), chains of CL=72.
__global__ __launch_bounds__(1024) void k4a_local(const float* __restrict__ Alogs,
        float* __restrict__ ws) {
    __shared__ float Pl[2][NC][NS];
    __shared__ float Hl[2][NC][NS];
    int blk = blockIdx.x;            // 768 = bk(8) * pair(96)
    int bk = blk / 96;
    int p = blk % 96;
    int k = bk & 3;
    int c = threadIdx.x >> 5;        // 0..31
    int n = threadIdx.x & 31;
    int dA = 2*p;
    float aA2 = -__expf(Alogs[((size_t)k*D_ + dA)*NS + n]) * 1.44269504f;
    float aB2 = -__expf(Alogs[((size_t)k*D_ + dA + 1)*NS + n]) * 1.44269504f;
    const float* dpA = ws + OFF_DELTA + (size_t)(bk*D_ + dA)*L_ + c*CL;
    const float* dpB = dpA + L_;
    const float* duA = ws + OFF_DU + ((size_t)(bk*NC + c)*D_ + dA)*CL;
    const float* duB = duA + CL;
    const float* Bsp = ws + OFF_BS + ((size_t)bk*L_ + c*CL)*NS;
    float hA = 0.f, hB = 0.f, PA = 1.f, PB = 1.f;

    float XdA[4], XdB[4], XuA[4], XuB[4], Xbn[4];
    float YdA[4], YdB[4], YuA[4], YuB[4], Ybn[4];
#define KL4(Pr, base) { \
    _Pragma("unroll") \
    for (int j = 0; j < 4; ++j) { \
        int l_ = (base) + j; \
        Pr##dA[j] = dpA[l_]; Pr##dB[j] = dpB[l_]; \
        Pr##uA[j] = duA[l_]; Pr##uB[j] = duB[l_]; \
        Pr##bn[j] = Bsp[l_*NS + n]; \
    } }
#define KC4(Pr) { \
    _Pragma("unroll") \
    for (int j = 0; j < 4; ++j) { \
        float eA = fexp2(Pr##dA[j] * aA2); \
        float eB = fexp2(Pr##dB[j] * aB2); \
        hA = fmaf(hA, eA, Pr##uA[j]*Pr##bn[j]); \
        hB = fmaf(hB, eB, Pr##uB[j]*Pr##bn[j]); \
        PA *= eA; \
        PB *= eB; \
    } }
    KL4(X, 0);
    for (int lb = 0; lb < CL; lb += 8) {
        KL4(Y, lb+4);
        KC4(X);
        if (lb + 8 < CL) KL4(X, lb+8);
        KC4(Y);
    }
#undef KL4
#undef KC4
    Pl[0][c][n] = PA; Pl[1][c][n] = PB;
    Hl[0][c][n] = hA; Hl[1][c][n] = hB;
    __syncthreads();
    if (threadIdx.x < 64) {
        int ch = threadIdx.x >> 5, nn = threadIdx.x & 31;
        int chain = bk*D_ + dA + ch;
        float h = 0.f;
        #pragma unroll
        for (int cc = 0; cc < NC; ++cc) {
            ws[h0_off(cc, chain, nn)] = h;
            h = fmaf(h, Pl[ch][cc][nn], Hl[ch][cc][nn]);
        }
    }
}

// ---------------- K4c: replay with true h0; y staged in LDS ----------------
// block = (bk, chunk, 32-d group); grid 1536 = 8*32*6; 512 threads.
// Double-buffered register prefetch; chains of CL=72.
__global__ __launch_bounds__(512) void k4c_scan(const float* __restrict__ Alogs,
        float* __restrict__ ws) {
    __shared__ float yld[CL*32];     // [l][dd] 9.2KB
    int blk = blockIdx.x;            // 1536 = bk(8) * c(32) * dg(6)
    int dg = blk % 6;
    int c  = (blk / 6) % NC;
    int bk = blk / (6*NC);
    int k = bk & 3;
    int sw = threadIdx.x >> 5;
    int n  = threadIdx.x & 31;
    int dA = dg*32 + sw;
    int dB = dA + 16;
    float aA2 = -__expf(Alogs[((size_t)k*D_ + dA)*NS + n]) * 1.44269504f;
    float aB2 = -__expf(Alogs[((size_t)k*D_ + dB)*NS + n]) * 1.44269504f;
    const float* dpA = ws + OFF_DELTA + (size_t)(bk*D_ + dA)*L_ + c*CL;
    const float* dpB = dpA + 16*L_;
    const float* duA = ws + OFF_DU + ((size_t)(bk*NC + c)*D_ + dA)*CL;
    const float* duB = duA + 16*CL;
    const float* Bsp = ws + OFF_BS + ((size_t)bk*L_ + c*CL)*NS;
    const float* Csp = ws + OFF_CS + ((size_t)bk*L_ + c*CL)*NS;
    float hA = ws[h0_off(c, bk*D_ + dA, n)];
    float hB = ws[h0_off(c, bk*D_ + dB, n)];
    int g = n >> 3;
    int off = ((g & 1) << 1) | (g >> 1);

    float XdA[4], XdB[4], XuA[4], XuB[4], Xbn[4], Xcn[4];
    float YdA[4], YdB[4], YuA[4], YuB[4], Ybn[4], Ycn[4];
#define CL4(Pr, base) { \
    _Pragma("unroll") \
    for (int j = 0; j < 4; ++j) { \
        int l_ = (base) + j; \
        Pr##dA[j] = dpA[l_]; Pr##dB[j] = dpB[l_]; \
        Pr##uA[j] = duA[l_]; Pr##uB[j] = duB[l_]; \
        Pr##bn[j] = Bsp[l_*NS + n]; \
        Pr##cn[j] = Csp[l_*NS + n]; \
    } }
#define CC4(Pr, lbase) { \
    float yA[4], yB[4]; \
    _Pragma("unroll") \
    for (int j = 0; j < 4; ++j) { \
        hA = fmaf(hA, fexp2(Pr##dA[j]*aA2), Pr##uA[j]*Pr##bn[j]); \
        hB = fmaf(hB, fexp2(Pr##dB[j]*aB2), Pr##uB[j]*Pr##bn[j]); \
        yA[j] = hA * Pr##cn[j]; yB[j] = hB * Pr##cn[j]; \
    } \
    _Pragma("unroll") \
    for (int j = 0; j < 4; ++j) { \
        yA[j] += __shfl_xor(yA[j], 16); \
        yB[j] += __shfl_xor(yB[j], 16); \
    } \
    float zA0 = (n & 16) ? yA[1] : yA[0]; \
    float zA1 = (n & 16) ? yA[3] : yA[2]; \
    float zB0 = (n & 16) ? yB[1] : yB[0]; \
    float zB1 = (n & 16) ? yB[3] : yB[2]; \
    zA0 += __shfl_xor(zA0, 8); zA1 += __shfl_xor(zA1, 8); \
    zB0 += __shfl_xor(zB0, 8); zB1 += __shfl_xor(zB1, 8); \
    float wA = (n & 8) ? zA1 : zA0; \
    float wB = (n & 8) ? zB1 : zB0; \
    wA += __shfl_xor(wA, 4); wA += __shfl_xor(wA, 2); wA += __shfl_xor(wA, 1); \
    wB += __shfl_xor(wB, 4); wB += __shfl_xor(wB, 2); wB += __shfl_xor(wB, 1); \
    if ((n & 7) == 0) { \
        yld[((lbase) + off)*32 + sw]      = wA; \
        yld[((lbase) + off)*32 + sw + 16] = wB; \
    } }
    CL4(X, 0);
    for (int lb = 0; lb < CL; lb += 8) {
        CL4(Y, lb+4);
        CC4(X, lb);
        if (lb + 8 < CL) CL4(X, lb+8);
        CC4(Y, lb+4);
    }
#undef CL4
#undef CC4
    __syncthreads();
    // blk == (bk*NC + c)*6 + dg, so the YS cell is exactly the du cell read
    float* ysp = ws + OFF_YS + (size_t)blk*(CL*32);
    #pragma unroll
    for (int it = 0; it < 5; ++it) {
        int idx = it*512 + threadIdx.x;
        if (idx < CL*32) ysp[idx] = yld[idx];
    }
}

// ---------------- K56: merge 4 dirs + D-term + LN + SiLU(z) + out_proj + res
// grid 576 = b(2) * ltile8(288); 256 threads. P=8 positions per block.
__global__ __launch_bounds__(256) void k56_fused(const float* __restrict__ lnw,
        const float* __restrict__ lnb, const float* __restrict__ dsp,
        const float* __restrict__ w, const float* __restrict__ xin,
        float* __restrict__ out, const float* __restrict__ ws) {
    __shared__ __align__(16) float Ys[48*32];    // [dq][p*4+sub], 8 p
    __shared__ float redS[8][33];
    __shared__ float redQ[8][33];
    __shared__ float muS[8], rsS[8];
    __shared__ float Dsum[D_];
    __shared__ float outT[8*97];
    int blk = blockIdx.x;
    int b = blk / 288;
    int l0 = (blk % 288) * 8;
    int tid = threadIdx.x;
    int hh = l0 / W_;       // tile stays within one row (48/8 = 6 tiles/row)
    int w0b = l0 % W_;
    if (tid < D_) Dsum[tid] = dsp[tid] + dsp[D_+tid] + dsp[2*D_+tid] + dsp[3*D_+tid];
    const float* ysb = ws + OFF_YS;
    int bk0 = b*K_;
    // ---- stage merged 4-direction y into GEMM layout (blocked YS reads) ----
    #pragma unroll
    for (int it = 0; it < 2; ++it) {
        int i4 = it*256 + tid;        // 384 float4
        if (i4 < 384) {
            int p = i4 / 48, c48 = i4 % 48;
            int pos    = l0 + p;
            int posr   = L_ - 1 - pos;
            int poswh  = (w0b + p)*H_ + hh;
            int poswhr = L_ - 1 - poswh;
            int dsub = c48 >> 3;          // dg
            int doff = (c48 & 7) * 4;     // d' within 32-group
            float4 a  = *(const float4*)&ysb[((((size_t)(bk0+0)*NC + pos   /CL)*6 + dsub)*CL + pos   %CL)*32 + doff];
            float4 bb = *(const float4*)&ysb[((((size_t)(bk0+2)*NC + posr  /CL)*6 + dsub)*CL + posr  %CL)*32 + doff];
            float4 cc = *(const float4*)&ysb[((((size_t)(bk0+1)*NC + poswh /CL)*6 + dsub)*CL + poswh %CL)*32 + doff];
            float4 dd = *(const float4*)&ysb[((((size_t)(bk0+3)*NC + poswhr/CL)*6 + dsub)*CL + poswhr%CL)*32 + doff];
            float4 v = make_float4(a.x+bb.x+cc.x+dd.x, a.y+bb.y+cc.y+dd.y,
                                   a.z+bb.z+cc.z+dd.z, a.w+bb.w+cc.w+dd.w);
            *(float4*)&Ys[c48*32 + p*4] = v;
        }
    }
    __syncthreads();
    // ---- add Dsum_d * xhw[b,d,pos] (the folded Ds*u term, pre-LN) ----
    const float* xhw = ws + OFF_XHW;
    #pragma unroll
    for (int it = 0; it < 6; ++it) {
        int idx = it*256 + tid;       // 1536 = d(192) x p(8)
        int d = idx >> 3, p = idx & 7;
        float xv = xhw[(size_t)(b*D_ + d)*L_ + l0 + p];
        Ys[(d>>2)*32 + p*4 + (d&3)] += Dsum[d]*xv;
    }
    __syncthreads();
    // ---- per-position LN partial sums: 32 groups per position ----
    {
        int p = tid & 7, g = tid >> 3;   // g in [0,32)
        float s = 0.f, q = 0.f;
        {   // quad g
            #pragma unroll
            for (int sx = 0; sx < 4; ++sx) {
                float v = Ys[g*32 + p*4 + sx];
                s += v; q += v*v;
            }
        }
        if (g < 16) {   // quad g+32
            #pragma unroll
            for (int sx = 0; sx < 4; ++sx) {
                float v = Ys[(g+32)*32 + p*4 + sx];
                s += v; q += v*v;
            }
        }
        redS[p][g] = s; redQ[p][g] = q;
    }
    __syncthreads();
    if (tid < 8) {
        float s = 0.f, q = 0.f;
        #pragma unroll
        for (int g = 0; g < 32; ++g) { s += redS[tid][g]; q += redQ[tid][g]; }
        float mu  = s * (1.f/192.f);
        float var = q * (1.f/192.f) - mu*mu;
        muS[tid] = mu;
        rsS[tid] = rsqrtf(var + 1e-5f);
    }
    __syncthreads();
    // ---- LN + SiLU(z) gate, in place ----
    #pragma unroll
    for (int it = 0; it < 2; ++it) {
        int i4 = it*256 + tid;
        if (i4 < 384) {
            int p = i4 / 48, c48 = i4 % 48;
            int pos = l0 + p;
            float4 v  = *(float4*)&Ys[c48*32 + p*4];
            float4 wv = *(const float4*)(lnw + c48*4);
            float4 bv = *(const float4*)(lnb + c48*4);
            float4 zv = *(const float4*)(ws + OFF_Z + (size_t)(b*L_ + pos)*D_ + c48*4);
            float mu = muS[p], rs = rsS[p];
            float o0 = ((v.x-mu)*rs*wv.x + bv.x) * (zv.x / (1.f + __expf(-zv.x)));
            float o1 = ((v.y-mu)*rs*wv.y + bv.y) * (zv.y / (1.f + __expf(-zv.y)));
            float o2 = ((v.z-mu)*rs*wv.z + bv.z) * (zv.z / (1.f + __expf(-zv.z)));
            float o3 = ((v.w-mu)*rs*wv.w + bv.w) * (zv.w / (1.f + __expf(-zv.w)));
            *(float4*)&Ys[c48*32 + p*4] = make_float4(o0, o1, o2, o3);
        }
    }
    __syncthreads();
    // ---- out_proj GEMM: 8 l x 32 cg, 3 outputs/thread (full 96 channels) --
    int l = tid & 7, cg = tid >> 3;
    float acc[3] = {0.f, 0.f, 0.f};
    const float4* wp[3];
    #pragma unroll
    for (int i = 0; i < 3; ++i) {
        int c = cg*3 + i;
        wp[i] = (const float4*)(w + (size_t)c*D_);
    }
    for (int q = 0; q < 48; ++q) {
        float4 xr = *(const float4*)&Ys[q*32 + l*4];
        #pragma unroll
        for (int i = 0; i < 3; ++i) {
            float4 wv = wp[i][q];
            acc[i] += xr.x*wv.x + xr.y*wv.y + xr.z*wv.z + xr.w*wv.w;
        }
    }
    #pragma unroll
    for (int i = 0; i < 3; ++i) outT[l*97 + cg*3 + i] = acc[i];
    __syncthreads();
    // ---- coalesced write with residual ----
    #pragma unroll
    for (int it = 0; it < 3; ++it) {
        int idx = it*256 + tid;       // 768 outputs
        int p = idx / 96, cc = idx % 96;
        size_t o = (size_t)(b*L_ + l0 + p)*C_ + cc;
        out[o] = xin[o] + outT[p*97 + cc];
    }
}

extern "C" void kernel_launch(void* const* d_in, const int* in_sizes, int n_in,
                              void* d_out, int out_size, void* d_ws, size_t ws_size,
                              hipStream_t stream) {
    const float* x        = (const float*)d_in[0];
    const float* in_proj  = (const float*)d_in[1];
    const float* conv_w   = (const float*)d_in[2];
    const float* conv_b   = (const float*)d_in[3];
    const float* x_proj_w = (const float*)d_in[4];
    const float* dt_w     = (const float*)d_in[5];
    const float* dt_b     = (const float*)d_in[6];
    const float* A_logs   = (const float*)d_in[7];
    const float* Ds       = (const float*)d_in[8];
    const float* ln_w     = (const float*)d_in[9];
    const float* ln_b     = (const float*)d_in[10];
    const float* out_w    = (const float*)d_in[11];
    float* out = (float*)d_out;
    float* ws  = (float*)d_ws;

    k1_inproj <<<576,  256, 0, stream>>>(x, in_proj, ws);
    k2_conv   <<<768,  256, 0, stream>>>(conv_w, conv_b, ws);
    k3_xproj  <<<1152, 256, 0, stream>>>(x_proj_w, dt_w, dt_b, ws);
    k4a_local <<<768, 1024, 0, stream>>>(A_logs, ws);
    k4c_scan  <<<1536, 512, 0, stream>>>(A_logs, ws);
    k56_fused <<<576,  256, 0, stream>>>(ln_w, ln_b, Ds, out_w, x, out, ws);
}

// Round 18
// 267.901 us; speedup vs baseline: 1.0501x; 1.0501x over previous
//
#include <hip/hip_runtime.h>
#include <math.h>

#define B_ 2
#define H_ 48
#define W_ 48
#define C_ 96
#define D_ 192
#define L_ 2304   // H_*W_
#define K_ 4
#define NS 32     // D_STATE
#define RK 6      // DT_RANK
#define CD 70     // RK + 2*NS

#define NC 16         // scan chunks
#define CL (L_/NC)    // 144 steps per chunk
#define NCH (B_*K_*D_)// 1536 chains

// workspace offsets (floats)
#define BDL (B_*D_*L_)                    // 884736
#define OFF_Z      0                      // z stored (b, l, d)
#define OFF_XPRE   (OFF_Z    + BDL)
#define OFF_XHW    (OFF_XPRE + BDL)
#define OFF_XWH    (OFF_XHW  + BDL)
#define OFF_DELTA  (OFF_XWH  + BDL)      // size B*K*D*L, layout (b,k,d,l)
#define OFF_BS     (OFF_DELTA+ B_*K_*D_*L_)  // (b,k,l,n)
#define OFF_CS     (OFF_BS   + B_*K_*L_*NS)
#define OFF_YS     (OFF_CS   + B_*K_*L_*NS)  // blocked: [bk][c][dg][lc][32]
#define OFF_YF     (OFF_YS   + B_*K_*L_*D_)

// DU aliases the YS region: du layout [bk][c][d(192)][lc(144)].
#define OFF_DU     OFF_YS

// H0 scratch: NCH*NC*NS = 786432 floats in the YF region (separate from YS).
#define OFF_H0     OFF_YF

// raw v_exp_f32 (exp2); log2e folded into the per-lane A constant once.
__device__ __forceinline__ float fexp2(float x) {
    float r; asm("v_exp_f32 %0, %1" : "=v"(r) : "v"(x)); return r;
}

// ---------------- K1: in_proj GEMM ------------------------------------------
// grid 576 = b(2) * ltile32(72) * es(4); es 0,1 -> xpre (b,d,pos); 2,3 -> z (b,l,d)
__global__ __launch_bounds__(256) void k1_inproj(const float* __restrict__ x,
        const float* __restrict__ w, float* __restrict__ ws) {
    __shared__ __align__(16) float Xs[24*128];   // [cq][l*4+sub], 32 l
    int blk = blockIdx.x;
    int b = blk / 288;
    int rem = blk % 288;
    int l0 = (rem >> 2) * 32;
    int es = rem & 3;
    int tid = threadIdx.x;
    const float4* xs4 = (const float4*)(x + (size_t)(b*L_ + l0)*C_);
    #pragma unroll
    for (int it = 0; it < 3; ++it) {
        int i4 = it*256 + tid;        // 768 float4 = 3072 floats
        float4 v = xs4[i4];
        int idx4 = i4*4;
        int p = idx4 / 96, c = idx4 % 96;   // c % 4 == 0
        *(float4*)&Xs[(c>>2)*128 + p*4] = v;
    }
    __syncthreads();
    int l = tid & 31, eg = tid >> 5;
    int pos = l0 + l;
    float acc[12];
    #pragma unroll
    for (int i = 0; i < 12; ++i) acc[i] = 0.f;
    const float4* wp[12];
    #pragma unroll
    for (int i = 0; i < 12; ++i) {
        int e = es*96 + eg*12 + i;
        wp[i] = (const float4*)(w + (size_t)e*96);
    }
    for (int q = 0; q < 24; ++q) {
        float4 xr = *(const float4*)&Xs[q*128 + l*4];
        #pragma unroll
        for (int i = 0; i < 12; ++i) {
            float4 wv = wp[i][q];
            acc[i] += xr.x*wv.x + xr.y*wv.y + xr.z*wv.z + xr.w*wv.w;
        }
    }
    if (es < 2) {
        float* xpre = ws + OFF_XPRE;
        #pragma unroll
        for (int i = 0; i < 12; ++i) {
            int e = es*96 + eg*12 + i;
            xpre[(size_t)(b*D_ + e)*L_ + pos] = acc[i];
        }
    } else {
        float* zp = ws + OFF_Z + (size_t)(b*L_ + pos)*D_ + (es-2)*96 + eg*12;
        #pragma unroll
        for (int q = 0; q < 3; ++q)
            *(float4*)&zp[q*4] = make_float4(acc[q*4], acc[q*4+1], acc[q*4+2], acc[q*4+3]);
    }
}

// ---------------- K2: depthwise 3x3 conv + SiLU, half-image blocks ----------
__global__ __launch_bounds__(256) void k2_conv(const float* __restrict__ cw,
        const float* __restrict__ cb, float* __restrict__ ws) {
    __shared__ float img[26*48];
    __shared__ float res[24*49];     // padded for transpose read
    int blk = blockIdx.x;            // 768 = bd*2 + half
    int bd = blk >> 1;
    int half = blk & 1;
    int d = bd % D_;
    int hh0 = half * 24;
    int tid = threadIdx.x;
    const float* xp = ws + OFF_XPRE + (size_t)bd*L_;
    for (int it = 0; it < 5; ++it) {
        int idx = it*256 + tid;
        if (idx < 26*48) {
            int gr = hh0 - 1 + idx/48;
            img[idx] = (gr >= 0 && gr < H_) ? xp[gr*48 + idx%48] : 0.f;
        }
    }
    float wr[9];
    #pragma unroll
    for (int j = 0; j < 9; ++j) wr[j] = cw[d*9 + j];
    float bias = cb[d];
    __syncthreads();
    float* hw = ws + OFF_XHW + (size_t)bd*L_ + hh0*48;
    for (int it = 0; it < 5; ++it) {
        int idx = it*256 + tid;
        if (idx < 24*48) {
            int r = idx/48, w0 = idx%48;
            float acc = bias;
            #pragma unroll
            for (int kh = 0; kh < 3; ++kh) {
                #pragma unroll
                for (int kw = 0; kw < 3; ++kw) {
                    int iw = w0 + kw - 1;
                    if (iw >= 0 && iw < W_)
                        acc = fmaf(img[(r+kh)*48 + iw], wr[kh*3 + kw], acc);
                }
            }
            float v = acc / (1.f + __expf(-acc));
            hw[idx] = v;
            res[r*49 + w0] = v;
        }
    }
    __syncthreads();
    float* wh = ws + OFF_XWH + (size_t)bd*L_;
    for (int it = 0; it < 5; ++it) {
        int idx = it*256 + tid;
        if (idx < 24*48) {
            int w0 = idx/24, r = idx%24;
            wh[w0*48 + hh0 + r] = res[r*49 + w0];
        }
    }
}

// ---------------- K3: x_proj matvec + dt_proj + softplus + B/C + du ---------
// grid 1152 = b(2) * k(4) * ltile16(144).
// R17 change: stage the 70x192 xpw k-slice in LDS (stride 196: 16B-aligned
// rows, 2-way bank aliasing = free) — removes the scattered per-iteration
// global weight reads that made the matvec latency-bound.
__global__ __launch_bounds__(256) void k3_xproj(const float* __restrict__ xpw,
        const float* __restrict__ dtw, const float* __restrict__ dtb,
        float* __restrict__ ws) {
    __shared__ __align__(16) float Xs[48*64];    // [dq][l*4+sub], 16 l
    __shared__ float xd[CD*17];                  // [c][l], pad 17
    __shared__ __align__(16) float Wl[CD*196];   // 54.9 KB staged weights
    int blk = blockIdx.x;
    int b = blk / 576;
    int rem = blk % 576;
    int k = rem / 144;
    int l0 = (rem % 144) * 16;
    int tid = threadIdx.x;
    // ---- stage weights: CD*48 = 3360 float4, coalesced ----
    const float4* wsrc = (const float4*)(xpw + (size_t)k*CD*D_);
    #pragma unroll
    for (int it = 0; it < 14; ++it) {
        int i4 = it*256 + tid;
        if (i4 < CD*48) {
            int c = i4 / 48, q = i4 % 48;
            float4 v = wsrc[i4];
            *(float4*)&Wl[c*196 + q*4] = v;
        }
    }
    const float* src = ws + ((k & 1) ? OFF_XWH : OFF_XHW);
    bool flip = (k >= 2);
    #pragma unroll
    for (int it = 0; it < 12; ++it) {
        int idx = it*256 + tid;
        int d = idx >> 4, l = idx & 15;
        int pos = flip ? (L_ - 1 - (l0 + l)) : (l0 + l);
        Xs[(d>>2)*64 + l*4 + (d&3)] = src[(size_t)(b*D_ + d)*L_ + pos];
    }
    __syncthreads();
    int l = tid & 15, cg = tid >> 4;    // 16 l x 16 cg
    {
        float acc[5] = {0.f, 0.f, 0.f, 0.f, 0.f};
        int cr[5];
        #pragma unroll
        for (int i = 0; i < 5; ++i) {
            int c = cg + 16*i;
            if (c >= CD) c = 0;          // guard OOB; result masked on write
            cr[i] = c*196;
        }
        for (int q = 0; q < 48; ++q) {
            float4 xr = *(const float4*)&Xs[q*64 + l*4];
            #pragma unroll
            for (int i = 0; i < 5; ++i) {
                float4 wv = *(const float4*)&Wl[cr[i] + q*4];
                acc[i] += xr.x*wv.x + xr.y*wv.y + xr.z*wv.z + xr.w*wv.w;
            }
        }
        #pragma unroll
        for (int i = 0; i < 5; ++i) {
            int c = cg + 16*i;
            if (c < CD) xd[c*17 + l] = acc[i];
        }
    }
    __syncthreads();
    {   // dt_proj + softplus -> deltas (b,k,d,l) AND du (blocked scan layout)
        float r[6];
        #pragma unroll
        for (int rr = 0; rr < 6; ++rr) r[rr] = xd[rr*17 + l];
        int bk = b*K_ + k;
        float* dout = ws + OFF_DELTA + (size_t)bk*D_*L_;
        int cch = l0 / CL;               // tiles of 16 never straddle CL=144
        int lc  = l0 - cch*CL + l;
        float* dup = ws + OFF_DU + ((size_t)(bk*NC + cch))*D_*CL;
        int dg = tid >> 4;
        for (int i = 0; i < 12; ++i) {
            int d = dg*12 + i;
            const float* wdt = dtw + ((size_t)k*D_ + d)*6;
            float acc = dtb[k*D_ + d];
            #pragma unroll
            for (int rr = 0; rr < 6; ++rr) acc = fmaf(r[rr], wdt[rr], acc);
            float sp = fmaxf(acc, 0.f) + log1pf(__expf(-fabsf(acc)));
            dout[(size_t)d*L_ + l0 + l] = sp;
            float uv = Xs[(d>>2)*64 + l*4 + (d&3)];   // u in scan order
            dup[(size_t)d*CL + lc] = sp * uv;
        }
    }
    {   // Bs/Cs -> (b,k,l,n)
        float* Bsp = ws + OFF_BS + ((size_t)(b*K_ + k)*L_ + l0)*NS;
        float* Csp = ws + OFF_CS + ((size_t)(b*K_ + k)*L_ + l0)*NS;
        int n = tid & 31, lq = tid >> 5;
        #pragma unroll
        for (int j = 0; j < 2; ++j) {
            int ll = lq + 8*j;
            Bsp[(size_t)ll*NS + n] = xd[(RK + n)*17 + ll];
            Csp[(size_t)ll*NS + n] = xd[(RK + NS + n)*17 + ll];
        }
    }
}

// ---------------- K4a: local chunk scan + in-LDS combine -> H0 --------------
// block = (bk, d-pair); 512 threads = 16 chunks x 32 states; 2 chains/lane.
// Double-buffered register prefetch (R14 mechanism, measured-passing twice).
__global__ __launch_bounds__(512) void k4a_local(const float* __restrict__ Alogs,
        float* __restrict__ ws) {
    __shared__ float Pl[2][NC][NS];
    __shared__ float Hl[2][NC][NS];
    int blk = blockIdx.x;            // 768 = bk(8) * pair(96)
    int bk = blk / 96;
    int p = blk % 96;
    int k = bk & 3;
    int c = threadIdx.x >> 5;
    int n = threadIdx.x & 31;
    int dA = 2*p;
    float aA2 = -__expf(Alogs[((size_t)k*D_ + dA)*NS + n]) * 1.44269504f;
    float aB2 = -__expf(Alogs[((size_t)k*D_ + dA + 1)*NS + n]) * 1.44269504f;
    const float* dpA = ws + OFF_DELTA + (size_t)(bk*D_ + dA)*L_ + c*CL;
    const float* dpB = dpA + L_;
    const float* duA = ws + OFF_DU + ((size_t)(bk*NC + c)*D_ + dA)*CL;
    const float* duB = duA + CL;
    const float* Bsp = ws + OFF_BS + ((size_t)bk*L_ + c*CL)*NS;
    float hA = 0.f, hB = 0.f, PA = 1.f, PB = 1.f;

    float XdA[4], XdB[4], XuA[4], XuB[4], Xbn[4];
    float YdA[4], YdB[4], YuA[4], YuB[4], Ybn[4];
#define KL4(Pr, base) { \
    _Pragma("unroll") \
    for (int j = 0; j < 4; ++j) { \
        int l_ = (base) + j; \
        Pr##dA[j] = dpA[l_]; Pr##dB[j] = dpB[l_]; \
        Pr##uA[j] = duA[l_]; Pr##uB[j] = duB[l_]; \
        Pr##bn[j] = Bsp[l_*NS + n]; \
    } }
#define KC4(Pr) { \
    _Pragma("unroll") \
    for (int j = 0; j < 4; ++j) { \
        float eA = fexp2(Pr##dA[j] * aA2); \
        float eB = fexp2(Pr##dB[j] * aB2); \
        hA = fmaf(hA, eA, Pr##uA[j]*Pr##bn[j]); \
        hB = fmaf(hB, eB, Pr##uB[j]*Pr##bn[j]); \
        PA *= eA; \
        PB *= eB; \
    } }
    KL4(X, 0);
    for (int lb = 0; lb < CL; lb += 8) {
        KL4(Y, lb+4);
        KC4(X);
        if (lb + 8 < CL) KL4(X, lb+8);
        KC4(Y);
    }
#undef KL4
#undef KC4
    Pl[0][c][n] = PA; Pl[1][c][n] = PB;
    Hl[0][c][n] = hA; Hl[1][c][n] = hB;
    __syncthreads();
    if (threadIdx.x < 64) {
        int ch = threadIdx.x >> 5, nn = threadIdx.x & 31;
        float* H0p = ws + OFF_H0 + (size_t)(bk*D_ + dA + ch)*NC*NS + nn;
        float h = 0.f;
        #pragma unroll
        for (int cc = 0; cc < NC; ++cc) {
            H0p[cc*NS] = h;
            h = fmaf(h, Pl[ch][cc][nn], Hl[ch][cc][nn]);
        }
    }
}

// ---------------- K4c: replay with true h0; y staged in LDS ----------------
// block = (bk, chunk, 32-d group); 512 threads = 16 subwaves x 2 chains.
// Double-buffered register prefetch (R14 mechanism, measured-passing twice).
__global__ __launch_bounds__(512) void k4c_scan(const float* __restrict__ Alogs,
        float* __restrict__ ws) {
    __shared__ float yld[CL*32];     // [l][dd] 18.4KB
    int blk = blockIdx.x;            // 768 = bk(8) * c(16) * dg(6)
    int dg = blk % 6;
    int c  = (blk / 6) % NC;
    int bk = blk / (6*NC);
    int k = bk & 3;
    int sw = threadIdx.x >> 5;
    int n  = threadIdx.x & 31;
    int dA = dg*32 + sw;
    int dB = dA + 16;
    float aA2 = -__expf(Alogs[((size_t)k*D_ + dA)*NS + n]) * 1.44269504f;
    float aB2 = -__expf(Alogs[((size_t)k*D_ + dB)*NS + n]) * 1.44269504f;
    const float* dpA = ws + OFF_DELTA + (size_t)(bk*D_ + dA)*L_ + c*CL;
    const float* dpB = dpA + 16*L_;
    const float* duA = ws + OFF_DU + ((size_t)(bk*NC + c)*D_ + dA)*CL;
    const float* duB = duA + 16*CL;
    const float* Bsp = ws + OFF_BS + ((size_t)bk*L_ + c*CL)*NS;
    const float* Csp = ws + OFF_CS + ((size_t)bk*L_ + c*CL)*NS;
    float hA = ws[OFF_H0 + (size_t)(bk*D_ + dA)*NC*NS + c*NS + n];
    float hB = ws[OFF_H0 + (size_t)(bk*D_ + dB)*NC*NS + c*NS + n];
    int g = n >> 3;
    int off = ((g & 1) << 1) | (g >> 1);

    float XdA[4], XdB[4], XuA[4], XuB[4], Xbn[4], Xcn[4];
    float YdA[4], YdB[4], YuA[4], YuB[4], Ybn[4], Ycn[4];
#define CL4(Pr, base) { \
    _Pragma("unroll") \
    for (int j = 0; j < 4; ++j) { \
        int l_ = (base) + j; \
        Pr##dA[j] = dpA[l_]; Pr##dB[j] = dpB[l_]; \
        Pr##uA[j] = duA[l_]; Pr##uB[j] = duB[l_]; \
        Pr##bn[j] = Bsp[l_*NS + n]; \
        Pr##cn[j] = Csp[l_*NS + n]; \
    } }
#define CC4(Pr, lbase) { \
    float yA[4], yB[4]; \
    _Pragma("unroll") \
    for (int j = 0; j < 4; ++j) { \
        hA = fmaf(hA, fexp2(Pr##dA[j]*aA2), Pr##uA[j]*Pr##bn[j]); \
        hB = fmaf(hB, fexp2(Pr##dB[j]*aB2), Pr##uB[j]*Pr##bn[j]); \
        yA[j] = hA * Pr##cn[j]; yB[j] = hB * Pr##cn[j]; \
    } \
    _Pragma("unroll") \
    for (int j = 0; j < 4; ++j) { \
        yA[j] += __shfl_xor(yA[j], 16); \
        yB[j] += __shfl_xor(yB[j], 16); \
    } \
    float zA0 = (n & 16) ? yA[1] : yA[0]; \
    float zA1 = (n & 16) ? yA[3] : yA[2]; \
    float zB0 = (n & 16) ? yB[1] : yB[0]; \
    float zB1 = (n & 16) ? yB[3] : yB[2]; \
    zA0 += __shfl_xor(zA0, 8); zA1 += __shfl_xor(zA1, 8); \
    zB0 += __shfl_xor(zB0, 8); zB1 += __shfl_xor(zB1, 8); \
    float wA = (n & 8) ? zA1 : zA0; \
    float wB = (n & 8) ? zB1 : zB0; \
    wA += __shfl_xor(wA, 4); wA += __shfl_xor(wA, 2); wA += __shfl_xor(wA, 1); \
    wB += __shfl_xor(wB, 4); wB += __shfl_xor(wB, 2); wB += __shfl_xor(wB, 1); \
    if ((n & 7) == 0) { \
        yld[((lbase) + off)*32 + sw]      = wA; \
        yld[((lbase) + off)*32 + sw + 16] = wB; \
    } }
    CL4(X, 0);
    for (int lb = 0; lb < CL; lb += 8) {
        CL4(Y, lb+4);
        CC4(X, lb);
        if (lb + 8 < CL) CL4(X, lb+8);
        CC4(Y, lb+4);
    }
#undef CL4
#undef CC4
    __syncthreads();
    // blk == (bk*NC + c)*6 + dg, so the YS cell is exactly the du cell read
    float* ysp = ws + OFF_YS + (size_t)blk*(CL*32);
    #pragma unroll
    for (int it = 0; it < 9; ++it) {
        int idx = it*512 + threadIdx.x;
        ysp[idx] = yld[idx];
    }
}

// ---------------- K56: merge 4 dirs + D-term + LN + SiLU(z) + out_proj + res
// grid 576 = b(2) * ltile8(288); 256 threads. P=8 positions per block.
__global__ __launch_bounds__(256) void k56_fused(const float* __restrict__ lnw,
        const float* __restrict__ lnb, const float* __restrict__ dsp,
        const float* __restrict__ w, const float* __restrict__ xin,
        float* __restrict__ out, const float* __restrict__ ws) {
    __shared__ __align__(16) float Ys[48*32];    // [dq][p*4+sub], 8 p
    __shared__ float redS[8][33];
    __shared__ float redQ[8][33];
    __shared__ float muS[8], rsS[8];
    __shared__ float Dsum[D_];
    __shared__ float outT[8*97];
    int blk = blockIdx.x;
    int b = blk / 288;
    int l0 = (blk % 288) * 8;
    int tid = threadIdx.x;
    int hh = l0 / W_;       // tile stays within one row (48/8 = 6 tiles/row)
    int w0b = l0 % W_;
    if (tid < D_) Dsum[tid] = dsp[tid] + dsp[D_+tid] + dsp[2*D_+tid] + dsp[3*D_+tid];
    const float* ysb = ws + OFF_YS;
    int bk0 = b*K_;
    // ---- stage merged 4-direction y into GEMM layout (blocked YS reads) ----
    #pragma unroll
    for (int it = 0; it < 2; ++it) {
        int i4 = it*256 + tid;        // 384 float4
        if (i4 < 384) {
            int p = i4 / 48, c48 = i4 % 48;
            int pos    = l0 + p;
            int posr   = L_ - 1 - pos;
            int poswh  = (w0b + p)*H_ + hh;
            int poswhr = L_ - 1 - poswh;
            int dsub = c48 >> 3;          // dg
            int doff = (c48 & 7) * 4;     // d' within 32-group
            float4 a  = *(const float4*)&ysb[((((size_t)(bk0+0)*NC + pos   /CL)*6 + dsub)*CL + pos   %CL)*32 + doff];
            float4 bb = *(const float4*)&ysb[((((size_t)(bk0+2)*NC + posr  /CL)*6 + dsub)*CL + posr  %CL)*32 + doff];
            float4 cc = *(const float4*)&ysb[((((size_t)(bk0+1)*NC + poswh /CL)*6 + dsub)*CL + poswh %CL)*32 + doff];
            float4 dd = *(const float4*)&ysb[((((size_t)(bk0+3)*NC + poswhr/CL)*6 + dsub)*CL + poswhr%CL)*32 + doff];
            float4 v = make_float4(a.x+bb.x+cc.x+dd.x, a.y+bb.y+cc.y+dd.y,
                                   a.z+bb.z+cc.z+dd.z, a.w+bb.w+cc.w+dd.w);
            *(float4*)&Ys[c48*32 + p*4] = v;
        }
    }
    __syncthreads();
    // ---- add Dsum_d * xhw[b,d,pos] (the folded Ds*u term, pre-LN) ----
    const float* xhw = ws + OFF_XHW;
    #pragma unroll
    for (int it = 0; it < 6; ++it) {
        int idx = it*256 + tid;       // 1536 = d(192) x p(8)
        int d = idx >> 3, p = idx & 7;
        float xv = xhw[(size_t)(b*D_ + d)*L_ + l0 + p];
        Ys[(d>>2)*32 + p*4 + (d&3)] += Dsum[d]*xv;
    }
    __syncthreads();
    // ---- per-position LN partial sums: 32 groups per position ----
    {
        int p = tid & 7, g = tid >> 3;   // g in [0,32)
        float s = 0.f, q = 0.f;
        {   // quad g
            #pragma unroll
            for (int sx = 0; sx < 4; ++sx) {
                float v = Ys[g*32 + p*4 + sx];
                s += v; q += v*v;
            }
        }
        if (g < 16) {   // quad g+32
            #pragma unroll
            for (int sx = 0; sx < 4; ++sx) {
                float v = Ys[(g+32)*32 + p*4 + sx];
                s += v; q += v*v;
            }
        }
        redS[p][g] = s; redQ[p][g] = q;
    }
    __syncthreads();
    if (tid < 8) {
        float s = 0.f, q = 0.f;
        #pragma unroll
        for (int g = 0; g < 32; ++g) { s += redS[tid][g]; q += redQ[tid][g]; }
        float mu  = s * (1.f/192.f);
        float var = q * (1.f/192.f) - mu*mu;
        muS[tid] = mu;
        rsS[tid] = rsqrtf(var + 1e-5f);
    }
    __syncthreads();
    // ---- LN + SiLU(z) gate, in place ----
    #pragma unroll
    for (int it = 0; it < 2; ++it) {
        int i4 = it*256 + tid;
        if (i4 < 384) {
            int p = i4 / 48, c48 = i4 % 48;
            int pos = l0 + p;
            float4 v  = *(float4*)&Ys[c48*32 + p*4];
            float4 wv = *(const float4*)(lnw + c48*4);
            float4 bv = *(const float4*)(lnb + c48*4);
            float4 zv = *(const float4*)(ws + OFF_Z + (size_t)(b*L_ + pos)*D_ + c48*4);
            float mu = muS[p], rs = rsS[p];
            float o0 = ((v.x-mu)*rs*wv.x + bv.x) * (zv.x / (1.f + __expf(-zv.x)));
            float o1 = ((v.y-mu)*rs*wv.y + bv.y) * (zv.y / (1.f + __expf(-zv.y)));
            float o2 = ((v.z-mu)*rs*wv.z + bv.z) * (zv.z / (1.f + __expf(-zv.z)));
            float o3 = ((v.w-mu)*rs*wv.w + bv.w) * (zv.w / (1.f + __expf(-zv.w)));
            *(float4*)&Ys[c48*32 + p*4] = make_float4(o0, o1, o2, o3);
        }
    }
    __syncthreads();
    // ---- out_proj GEMM: 8 l x 32 cg, 3 outputs/thread (full 96 channels) --
    int l = tid & 7, cg = tid >> 3;
    float acc[3] = {0.f, 0.f, 0.f};
    const float4* wp[3];
    #pragma unroll
    for (int i = 0; i < 3; ++i) {
        int c = cg*3 + i;
        wp[i] = (const float4*)(w + (size_t)c*D_);
    }
    for (int q = 0; q < 48; ++q) {
        float4 xr = *(const float4*)&Ys[q*32 + l*4];
        #pragma unroll
        for (int i = 0; i < 3; ++i) {
            float4 wv = wp[i][q];
            acc[i] += xr.x*wv.x + xr.y*wv.y + xr.z*wv.z + xr.w*wv.w;
        }
    }
    #pragma unroll
    for (int i = 0; i < 3; ++i) outT[l*97 + cg*3 + i] = acc[i];
    __syncthreads();
    // ---- coalesced write with residual ----
    #pragma unroll
    for (int it = 0; it < 3; ++it) {
        int idx = it*256 + tid;       // 768 outputs
        int p = idx / 96, cc = idx % 96;
        size_t o = (size_t)(b*L_ + l0 + p)*C_ + cc;
        out[o] = xin[o] + outT[p*97 + cc];
    }
}

extern "C" void kernel_launch(void* const* d_in, const int* in_sizes, int n_in,
                              void* d_out, int out_size, void* d_ws, size_t ws_size,
                              hipStream_t stream) {
    const float* x        = (const float*)d_in[0];
    const float* in_proj  = (const float*)d_in[1];
    const float* conv_w   = (const float*)d_in[2];
    const float* conv_b   = (const float*)d_in[3];
    const float* x_proj_w = (const float*)d_in[4];
    const float* dt_w     = (const float*)d_in[5];
    const float* dt_b     = (const float*)d_in[6];
    const float* A_logs   = (const float*)d_in[7];
    const float* Ds       = (const float*)d_in[8];
    const float* ln_w     = (const float*)d_in[9];
    const float* ln_b     = (const float*)d_in[10];
    const float* out_w    = (const float*)d_in[11];
    float* out = (float*)d_out;
    float* ws  = (float*)d_ws;

    k1_inproj <<<576,  256, 0, stream>>>(x, in_proj, ws);
    k2_conv   <<<768,  256, 0, stream>>>(conv_w, conv_b, ws);
    k3_xproj  <<<1152, 256, 0, stream>>>(x_proj_w, dt_w, dt_b, ws);
    k4a_local <<<768,  512, 0, stream>>>(A_logs, ws);
    k4c_scan  <<<768,  512, 0, stream>>>(A_logs, ws);
    k56_fused <<<576,  256, 0, stream>>>(ln_w, ln_b, Ds, out_w, x, out, ws);
}

// Round 19
// 252.261 us; speedup vs baseline: 1.1152x; 1.0620x over previous
//
#include <hip/hip_runtime.h>
#include <math.h>

#define B_ 2
#define H_ 48
#define W_ 48
#define C_ 96
#define D_ 192
#define L_ 2304   // H_*W_
#define K_ 4
#define NS 32     // D_STATE
#define RK 6      // DT_RANK
#define CD 70     // RK + 2*NS

#define NC 16         // scan chunks
#define CL (L_/NC)    // 144 steps per chunk
#define NCH (B_*K_*D_)// 1536 chains

// workspace offsets (floats)
#define BDL (B_*D_*L_)                    // 884736
#define OFF_Z      0                      // z stored (b, l, d)
#define OFF_XPRE   (OFF_Z    + BDL)
#define OFF_XHW    (OFF_XPRE + BDL)
#define OFF_XWH    (OFF_XHW  + BDL)
#define OFF_DELTA  (OFF_XWH  + BDL)      // size B*K*D*L, layout (b,k,d,l)
#define OFF_BS     (OFF_DELTA+ B_*K_*D_*L_)  // (b,k,l,n)
#define OFF_CS     (OFF_BS   + B_*K_*L_*NS)
#define OFF_YS     (OFF_CS   + B_*K_*L_*NS)  // blocked: [bk][c][dg][lc][32]
#define OFF_YF     (OFF_YS   + B_*K_*L_*D_)

// DU aliases the YS region: du layout [bk][c][d(192)][lc(144)].
#define OFF_DU     OFF_YS

// H0 scratch: NCH*NC*NS = 786432 floats in the YF region (separate from YS).
#define OFF_H0     OFF_YF

// raw v_exp_f32 (exp2); log2e folded into the per-lane A constant once.
__device__ __forceinline__ float fexp2(float x) {
    float r; asm("v_exp_f32 %0, %1" : "=v"(r) : "v"(x)); return r;
}

// ---------------- K1: in_proj GEMM ------------------------------------------
// grid 576 = b(2) * ltile32(72) * es(4); es 0,1 -> xpre (b,d,pos); 2,3 -> z (b,l,d)
// R18: stage the 96x96 es-slice of in_proj_w in LDS (36 KB, coalesced burst)
// — same proven fix as k3's R17 weight staging (removes scattered per-iter
// global weight reads). Reads are 2-rows-per-wave broadcasts: conflict-free.
__global__ __launch_bounds__(256) void k1_inproj(const float* __restrict__ x,
        const float* __restrict__ w, float* __restrict__ ws) {
    __shared__ __align__(16) float Xs[24*128];   // [cq][l*4+sub], 32 l
    __shared__ __align__(16) float Wl[96*96];    // 36 KB staged weight slice
    int blk = blockIdx.x;
    int b = blk / 288;
    int rem = blk % 288;
    int l0 = (rem >> 2) * 32;
    int es = rem & 3;
    int tid = threadIdx.x;
    // ---- stage weights: rows es*96 .. es*96+95 (contiguous 9216 floats) ----
    const float4* wsrc = (const float4*)(w + (size_t)(es*96)*96);
    #pragma unroll
    for (int it = 0; it < 9; ++it) {
        int i4 = it*256 + tid;        // 2304 float4
        *(float4*)&Wl[i4*4] = wsrc[i4];
    }
    const float4* xs4 = (const float4*)(x + (size_t)(b*L_ + l0)*C_);
    #pragma unroll
    for (int it = 0; it < 3; ++it) {
        int i4 = it*256 + tid;        // 768 float4 = 3072 floats
        float4 v = xs4[i4];
        int idx4 = i4*4;
        int p = idx4 / 96, c = idx4 % 96;   // c % 4 == 0
        *(float4*)&Xs[(c>>2)*128 + p*4] = v;
    }
    __syncthreads();
    int l = tid & 31, eg = tid >> 5;
    int pos = l0 + l;
    float acc[12];
    #pragma unroll
    for (int i = 0; i < 12; ++i) acc[i] = 0.f;
    for (int q = 0; q < 24; ++q) {
        float4 xr = *(const float4*)&Xs[q*128 + l*4];
        #pragma unroll
        for (int i = 0; i < 12; ++i) {
            float4 wv = *(const float4*)&Wl[(eg*12 + i)*96 + q*4];
            acc[i] += xr.x*wv.x + xr.y*wv.y + xr.z*wv.z + xr.w*wv.w;
        }
    }
    if (es < 2) {
        float* xpre = ws + OFF_XPRE;
        #pragma unroll
        for (int i = 0; i < 12; ++i) {
            int e = es*96 + eg*12 + i;
            xpre[(size_t)(b*D_ + e)*L_ + pos] = acc[i];
        }
    } else {
        float* zp = ws + OFF_Z + (size_t)(b*L_ + pos)*D_ + (es-2)*96 + eg*12;
        #pragma unroll
        for (int q = 0; q < 3; ++q)
            *(float4*)&zp[q*4] = make_float4(acc[q*4], acc[q*4+1], acc[q*4+2], acc[q*4+3]);
    }
}

// ---------------- K2: depthwise 3x3 conv + SiLU, half-image blocks ----------
__global__ __launch_bounds__(256) void k2_conv(const float* __restrict__ cw,
        const float* __restrict__ cb, float* __restrict__ ws) {
    __shared__ float img[26*48];
    __shared__ float res[24*49];     // padded for transpose read
    int blk = blockIdx.x;            // 768 = bd*2 + half
    int bd = blk >> 1;
    int half = blk & 1;
    int d = bd % D_;
    int hh0 = half * 24;
    int tid = threadIdx.x;
    const float* xp = ws + OFF_XPRE + (size_t)bd*L_;
    for (int it = 0; it < 5; ++it) {
        int idx = it*256 + tid;
        if (idx < 26*48) {
            int gr = hh0 - 1 + idx/48;
            img[idx] = (gr >= 0 && gr < H_) ? xp[gr*48 + idx%48] : 0.f;
        }
    }
    float wr[9];
    #pragma unroll
    for (int j = 0; j < 9; ++j) wr[j] = cw[d*9 + j];
    float bias = cb[d];
    __syncthreads();
    float* hw = ws + OFF_XHW + (size_t)bd*L_ + hh0*48;
    for (int it = 0; it < 5; ++it) {
        int idx = it*256 + tid;
        if (idx < 24*48) {
            int r = idx/48, w0 = idx%48;
            float acc = bias;
            #pragma unroll
            for (int kh = 0; kh < 3; ++kh) {
                #pragma unroll
                for (int kw = 0; kw < 3; ++kw) {
                    int iw = w0 + kw - 1;
                    if (iw >= 0 && iw < W_)
                        acc = fmaf(img[(r+kh)*48 + iw], wr[kh*3 + kw], acc);
                }
            }
            float v = acc / (1.f + __expf(-acc));
            hw[idx] = v;
            res[r*49 + w0] = v;
        }
    }
    __syncthreads();
    float* wh = ws + OFF_XWH + (size_t)bd*L_;
    for (int it = 0; it < 5; ++it) {
        int idx = it*256 + tid;
        if (idx < 24*48) {
            int w0 = idx/24, r = idx%24;
            wh[w0*48 + hh0 + r] = res[r*49 + w0];
        }
    }
}

// ---------------- K3: x_proj matvec + dt_proj + softplus + B/C + du ---------
// grid 1152 = b(2) * k(4) * ltile16(144). Weights staged in LDS (R17, +12us).
__global__ __launch_bounds__(256) void k3_xproj(const float* __restrict__ xpw,
        const float* __restrict__ dtw, const float* __restrict__ dtb,
        float* __restrict__ ws) {
    __shared__ __align__(16) float Xs[48*64];    // [dq][l*4+sub], 16 l
    __shared__ float xd[CD*17];                  // [c][l], pad 17
    __shared__ __align__(16) float Wl[CD*196];   // 54.9 KB staged weights
    int blk = blockIdx.x;
    int b = blk / 576;
    int rem = blk % 576;
    int k = rem / 144;
    int l0 = (rem % 144) * 16;
    int tid = threadIdx.x;
    // ---- stage weights: CD*48 = 3360 float4, coalesced ----
    const float4* wsrc = (const float4*)(xpw + (size_t)k*CD*D_);
    #pragma unroll
    for (int it = 0; it < 14; ++it) {
        int i4 = it*256 + tid;
        if (i4 < CD*48) {
            int c = i4 / 48, q = i4 % 48;
            float4 v = wsrc[i4];
            *(float4*)&Wl[c*196 + q*4] = v;
        }
    }
    const float* src = ws + ((k & 1) ? OFF_XWH : OFF_XHW);
    bool flip = (k >= 2);
    #pragma unroll
    for (int it = 0; it < 12; ++it) {
        int idx = it*256 + tid;
        int d = idx >> 4, l = idx & 15;
        int pos = flip ? (L_ - 1 - (l0 + l)) : (l0 + l);
        Xs[(d>>2)*64 + l*4 + (d&3)] = src[(size_t)(b*D_ + d)*L_ + pos];
    }
    __syncthreads();
    int l = tid & 15, cg = tid >> 4;    // 16 l x 16 cg
    {
        float acc[5] = {0.f, 0.f, 0.f, 0.f, 0.f};
        int cr[5];
        #pragma unroll
        for (int i = 0; i < 5; ++i) {
            int c = cg + 16*i;
            if (c >= CD) c = 0;          // guard OOB; result masked on write
            cr[i] = c*196;
        }
        for (int q = 0; q < 48; ++q) {
            float4 xr = *(const float4*)&Xs[q*64 + l*4];
            #pragma unroll
            for (int i = 0; i < 5; ++i) {
                float4 wv = *(const float4*)&Wl[cr[i] + q*4];
                acc[i] += xr.x*wv.x + xr.y*wv.y + xr.z*wv.z + xr.w*wv.w;
            }
        }
        #pragma unroll
        for (int i = 0; i < 5; ++i) {
            int c = cg + 16*i;
            if (c < CD) xd[c*17 + l] = acc[i];
        }
    }
    __syncthreads();
    {   // dt_proj + softplus -> deltas (b,k,d,l) AND du (blocked scan layout)
        float r[6];
        #pragma unroll
        for (int rr = 0; rr < 6; ++rr) r[rr] = xd[rr*17 + l];
        int bk = b*K_ + k;
        float* dout = ws + OFF_DELTA + (size_t)bk*D_*L_;
        int cch = l0 / CL;               // tiles of 16 never straddle CL=144
        int lc  = l0 - cch*CL + l;
        float* dup = ws + OFF_DU + ((size_t)(bk*NC + cch))*D_*CL;
        int dg = tid >> 4;
        for (int i = 0; i < 12; ++i) {
            int d = dg*12 + i;
            const float* wdt = dtw + ((size_t)k*D_ + d)*6;
            float acc = dtb[k*D_ + d];
            #pragma unroll
            for (int rr = 0; rr < 6; ++rr) acc = fmaf(r[rr], wdt[rr], acc);
            float sp = fmaxf(acc, 0.f) + log1pf(__expf(-fabsf(acc)));
            dout[(size_t)d*L_ + l0 + l] = sp;
            float uv = Xs[(d>>2)*64 + l*4 + (d&3)];   // u in scan order
            dup[(size_t)d*CL + lc] = sp * uv;
        }
    }
    {   // Bs/Cs -> (b,k,l,n)
        float* Bsp = ws + OFF_BS + ((size_t)(b*K_ + k)*L_ + l0)*NS;
        float* Csp = ws + OFF_CS + ((size_t)(b*K_ + k)*L_ + l0)*NS;
        int n = tid & 31, lq = tid >> 5;
        #pragma unroll
        for (int j = 0; j < 2; ++j) {
            int ll = lq + 8*j;
            Bsp[(size_t)ll*NS + n] = xd[(RK + n)*17 + ll];
            Csp[(size_t)ll*NS + n] = xd[(RK + NS + n)*17 + ll];
        }
    }
}

// ---------------- K4a: local chunk scan + in-LDS combine -> H0 --------------
// block = (bk, d-pair); 512 threads = 16 chunks x 32 states; 2 chains/lane.
// Double-buffered register prefetch (R14 mechanism, measured-passing twice).
__global__ __launch_bounds__(512) void k4a_local(const float* __restrict__ Alogs,
        float* __restrict__ ws) {
    __shared__ float Pl[2][NC][NS];
    __shared__ float Hl[2][NC][NS];
    int blk = blockIdx.x;            // 768 = bk(8) * pair(96)
    int bk = blk / 96;
    int p = blk % 96;
    int k = bk & 3;
    int c = threadIdx.x >> 5;
    int n = threadIdx.x & 31;
    int dA = 2*p;
    float aA2 = -__expf(Alogs[((size_t)k*D_ + dA)*NS + n]) * 1.44269504f;
    float aB2 = -__expf(Alogs[((size_t)k*D_ + dA + 1)*NS + n]) * 1.44269504f;
    const float* dpA = ws + OFF_DELTA + (size_t)(bk*D_ + dA)*L_ + c*CL;
    const float* dpB = dpA + L_;
    const float* duA = ws + OFF_DU + ((size_t)(bk*NC + c)*D_ + dA)*CL;
    const float* duB = duA + CL;
    const float* Bsp = ws + OFF_BS + ((size_t)bk*L_ + c*CL)*NS;
    float hA = 0.f, hB = 0.f, PA = 1.f, PB = 1.f;

    float XdA[4], XdB[4], XuA[4], XuB[4], Xbn[4];
    float YdA[4], YdB[4], YuA[4], YuB[4], Ybn[4];
#define KL4(Pr, base) { \
    _Pragma("unroll") \
    for (int j = 0; j < 4; ++j) { \
        int l_ = (base) + j; \
        Pr##dA[j] = dpA[l_]; Pr##dB[j] = dpB[l_]; \
        Pr##uA[j] = duA[l_]; Pr##uB[j] = duB[l_]; \
        Pr##bn[j] = Bsp[l_*NS + n]; \
    } }
#define KC4(Pr) { \
    _Pragma("unroll") \
    for (int j = 0; j < 4; ++j) { \
        float eA = fexp2(Pr##dA[j] * aA2); \
        float eB = fexp2(Pr##dB[j] * aB2); \
        hA = fmaf(hA, eA, Pr##uA[j]*Pr##bn[j]); \
        hB = fmaf(hB, eB, Pr##uB[j]*Pr##bn[j]); \
        PA *= eA; \
        PB *= eB; \
    } }
    KL4(X, 0);
    for (int lb = 0; lb < CL; lb += 8) {
        KL4(Y, lb+4);
        KC4(X);
        if (lb + 8 < CL) KL4(X, lb+8);
        KC4(Y);
    }
#undef KL4
#undef KC4
    Pl[0][c][n] = PA; Pl[1][c][n] = PB;
    Hl[0][c][n] = hA; Hl[1][c][n] = hB;
    __syncthreads();
    if (threadIdx.x < 64) {
        int ch = threadIdx.x >> 5, nn = threadIdx.x & 31;
        float* H0p = ws + OFF_H0 + (size_t)(bk*D_ + dA + ch)*NC*NS + nn;
        float h = 0.f;
        #pragma unroll
        for (int cc = 0; cc < NC; ++cc) {
            H0p[cc*NS] = h;
            h = fmaf(h, Pl[ch][cc][nn], Hl[ch][cc][nn]);
        }
    }
}

// ---------------- K4c: replay with true h0; y staged in LDS ----------------
// block = (bk, chunk, 32-d group); 512 threads = 16 subwaves x 2 chains.
// Double-buffered register prefetch (R14 mechanism, measured-passing twice).
__global__ __launch_bounds__(512) void k4c_scan(const float* __restrict__ Alogs,
        float* __restrict__ ws) {
    __shared__ float yld[CL*32];     // [l][dd] 18.4KB
    int blk = blockIdx.x;            // 768 = bk(8) * c(16) * dg(6)
    int dg = blk % 6;
    int c  = (blk / 6) % NC;
    int bk = blk / (6*NC);
    int k = bk & 3;
    int sw = threadIdx.x >> 5;
    int n  = threadIdx.x & 31;
    int dA = dg*32 + sw;
    int dB = dA + 16;
    float aA2 = -__expf(Alogs[((size_t)k*D_ + dA)*NS + n]) * 1.44269504f;
    float aB2 = -__expf(Alogs[((size_t)k*D_ + dB)*NS + n]) * 1.44269504f;
    const float* dpA = ws + OFF_DELTA + (size_t)(bk*D_ + dA)*L_ + c*CL;
    const float* dpB = dpA + 16*L_;
    const float* duA = ws + OFF_DU + ((size_t)(bk*NC + c)*D_ + dA)*CL;
    const float* duB = duA + 16*CL;
    const float* Bsp = ws + OFF_BS + ((size_t)bk*L_ + c*CL)*NS;
    const float* Csp = ws + OFF_CS + ((size_t)bk*L_ + c*CL)*NS;
    float hA = ws[OFF_H0 + (size_t)(bk*D_ + dA)*NC*NS + c*NS + n];
    float hB = ws[OFF_H0 + (size_t)(bk*D_ + dB)*NC*NS + c*NS + n];
    int g = n >> 3;
    int off = ((g & 1) << 1) | (g >> 1);

    float XdA[4], XdB[4], XuA[4], XuB[4], Xbn[4], Xcn[4];
    float YdA[4], YdB[4], YuA[4], YuB[4], Ybn[4], Ycn[4];
#define CL4(Pr, base) { \
    _Pragma("unroll") \
    for (int j = 0; j < 4; ++j) { \
        int l_ = (base) + j; \
        Pr##dA[j] = dpA[l_]; Pr##dB[j] = dpB[l_]; \
        Pr##uA[j] = duA[l_]; Pr##uB[j] = duB[l_]; \
        Pr##bn[j] = Bsp[l_*NS + n]; \
        Pr##cn[j] = Csp[l_*NS + n]; \
    } }
#define CC4(Pr, lbase) { \
    float yA[4], yB[4]; \
    _Pragma("unroll") \
    for (int j = 0; j < 4; ++j) { \
        hA = fmaf(hA, fexp2(Pr##dA[j]*aA2), Pr##uA[j]*Pr##bn[j]); \
        hB = fmaf(hB, fexp2(Pr##dB[j]*aB2), Pr##uB[j]*Pr##bn[j]); \
        yA[j] = hA * Pr##cn[j]; yB[j] = hB * Pr##cn[j]; \
    } \
    _Pragma("unroll") \
    for (int j = 0; j < 4; ++j) { \
        yA[j] += __shfl_xor(yA[j], 16); \
        yB[j] += __shfl_xor(yB[j], 16); \
    } \
    float zA0 = (n & 16) ? yA[1] : yA[0]; \
    float zA1 = (n & 16) ? yA[3] : yA[2]; \
    float zB0 = (n & 16) ? yB[1] : yB[0]; \
    float zB1 = (n & 16) ? yB[3] : yB[2]; \
    zA0 += __shfl_xor(zA0, 8); zA1 += __shfl_xor(zA1, 8); \
    zB0 += __shfl_xor(zB0, 8); zB1 += __shfl_xor(zB1, 8); \
    float wA = (n & 8) ? zA1 : zA0; \
    float wB = (n & 8) ? zB1 : zB0; \
    wA += __shfl_xor(wA, 4); wA += __shfl_xor(wA, 2); wA += __shfl_xor(wA, 1); \
    wB += __shfl_xor(wB, 4); wB += __shfl_xor(wB, 2); wB += __shfl_xor(wB, 1); \
    if ((n & 7) == 0) { \
        yld[((lbase) + off)*32 + sw]      = wA; \
        yld[((lbase) + off)*32 + sw + 16] = wB; \
    } }
    CL4(X, 0);
    for (int lb = 0; lb < CL; lb += 8) {
        CL4(Y, lb+4);
        CC4(X, lb);
        if (lb + 8 < CL) CL4(X, lb+8);
        CC4(Y, lb+4);
    }
#undef CL4
#undef CC4
    __syncthreads();
    // blk == (bk*NC + c)*6 + dg, so the YS cell is exactly the du cell read
    float* ysp = ws + OFF_YS + (size_t)blk*(CL*32);
    #pragma unroll
    for (int it = 0; it < 9; ++it) {
        int idx = it*512 + threadIdx.x;
        ysp[idx] = yld[idx];
    }
}

// ---------------- K56: merge 4 dirs + D-term + LN + SiLU(z) + out_proj + res
// grid 576 = b(2) * ltile8(288); 256 threads. P=8 positions per block.
__global__ __launch_bounds__(256) void k56_fused(const float* __restrict__ lnw,
        const float* __restrict__ lnb, const float* __restrict__ dsp,
        const float* __restrict__ w, const float* __restrict__ xin,
        float* __restrict__ out, const float* __restrict__ ws) {
    __shared__ __align__(16) float Ys[48*32];    // [dq][p*4+sub], 8 p
    __shared__ float redS[8][33];
    __shared__ float redQ[8][33];
    __shared__ float muS[8], rsS[8];
    __shared__ float Dsum[D_];
    __shared__ float outT[8*97];
    int blk = blockIdx.x;
    int b = blk / 288;
    int l0 = (blk % 288) * 8;
    int tid = threadIdx.x;
    int hh = l0 / W_;       // tile stays within one row (48/8 = 6 tiles/row)
    int w0b = l0 % W_;
    if (tid < D_) Dsum[tid] = dsp[tid] + dsp[D_+tid] + dsp[2*D_+tid] + dsp[3*D_+tid];
    const float* ysb = ws + OFF_YS;
    int bk0 = b*K_;
    // ---- stage merged 4-direction y into GEMM layout (blocked YS reads) ----
    #pragma unroll
    for (int it = 0; it < 2; ++it) {
        int i4 = it*256 + tid;        // 384 float4
        if (i4 < 384) {
            int p = i4 / 48, c48 = i4 % 48;
            int pos    = l0 + p;
            int posr   = L_ - 1 - pos;
            int poswh  = (w0b + p)*H_ + hh;
            int poswhr = L_ - 1 - poswh;
            int dsub = c48 >> 3;          // dg
            int doff = (c48 & 7) * 4;     // d' within 32-group
            float4 a  = *(const float4*)&ysb[((((size_t)(bk0+0)*NC + pos   /CL)*6 + dsub)*CL + pos   %CL)*32 + doff];
            float4 bb = *(const float4*)&ysb[((((size_t)(bk0+2)*NC + posr  /CL)*6 + dsub)*CL + posr  %CL)*32 + doff];
            float4 cc = *(const float4*)&ysb[((((size_t)(bk0+1)*NC + poswh /CL)*6 + dsub)*CL + poswh %CL)*32 + doff];
            float4 dd = *(const float4*)&ysb[((((size_t)(bk0+3)*NC + poswhr/CL)*6 + dsub)*CL + poswhr%CL)*32 + doff];
            float4 v = make_float4(a.x+bb.x+cc.x+dd.x, a.y+bb.y+cc.y+dd.y,
                                   a.z+bb.z+cc.z+dd.z, a.w+bb.w+cc.w+dd.w);
            *(float4*)&Ys[c48*32 + p*4] = v;
        }
    }
    __syncthreads();
    // ---- add Dsum_d * xhw[b,d,pos] (the folded Ds*u term, pre-LN) ----
    const float* xhw = ws + OFF_XHW;
    #pragma unroll
    for (int it = 0; it < 6; ++it) {
        int idx = it*256 + tid;       // 1536 = d(192) x p(8)
        int d = idx >> 3, p = idx & 7;
        float xv = xhw[(size_t)(b*D_ + d)*L_ + l0 + p];
        Ys[(d>>2)*32 + p*4 + (d&3)] += Dsum[d]*xv;
    }
    __syncthreads();
    // ---- per-position LN partial sums: 32 groups per position ----
    {
        int p = tid & 7, g = tid >> 3;   // g in [0,32)
        float s = 0.f, q = 0.f;
        {   // quad g
            #pragma unroll
            for (int sx = 0; sx < 4; ++sx) {
                float v = Ys[g*32 + p*4 + sx];
                s += v; q += v*v;
            }
        }
        if (g < 16) {   // quad g+32
            #pragma unroll
            for (int sx = 0; sx < 4; ++sx) {
                float v = Ys[(g+32)*32 + p*4 + sx];
                s += v; q += v*v;
            }
        }
        redS[p][g] = s; redQ[p][g] = q;
    }
    __syncthreads();
    if (tid < 8) {
        float s = 0.f, q = 0.f;
        #pragma unroll
        for (int g = 0; g < 32; ++g) { s += redS[tid][g]; q += redQ[tid][g]; }
        float mu  = s * (1.f/192.f);
        float var = q * (1.f/192.f) - mu*mu;
        muS[tid] = mu;
        rsS[tid] = rsqrtf(var + 1e-5f);
    }
    __syncthreads();
    // ---- LN + SiLU(z) gate, in place ----
    #pragma unroll
    for (int it = 0; it < 2; ++it) {
        int i4 = it*256 + tid;
        if (i4 < 384) {
            int p = i4 / 48, c48 = i4 % 48;
            int pos = l0 + p;
            float4 v  = *(float4*)&Ys[c48*32 + p*4];
            float4 wv = *(const float4*)(lnw + c48*4);
            float4 bv = *(const float4*)(lnb + c48*4);
            float4 zv = *(const float4*)(ws + OFF_Z + (size_t)(b*L_ + pos)*D_ + c48*4);
            float mu = muS[p], rs = rsS[p];
            float o0 = ((v.x-mu)*rs*wv.x + bv.x) * (zv.x / (1.f + __expf(-zv.x)));
            float o1 = ((v.y-mu)*rs*wv.y + bv.y) * (zv.y / (1.f + __expf(-zv.y)));
            float o2 = ((v.z-mu)*rs*wv.z + bv.z) * (zv.z / (1.f + __expf(-zv.z)));
            float o3 = ((v.w-mu)*rs*wv.w + bv.w) * (zv.w / (1.f + __expf(-zv.w)));
            *(float4*)&Ys[c48*32 + p*4] = make_float4(o0, o1, o2, o3);
        }
    }
    __syncthreads();
    // ---- out_proj GEMM: 8 l x 32 cg, 3 outputs/thread (full 96 channels) --
    int l = tid & 7, cg = tid >> 3;
    float acc[3] = {0.f, 0.f, 0.f};
    const float4* wp[3];
    #pragma unroll
    for (int i = 0; i < 3; ++i) {
        int c = cg*3 + i;
        wp[i] = (const float4*)(w + (size_t)c*D_);
    }
    for (int q = 0; q < 48; ++q) {
        float4 xr = *(const float4*)&Ys[q*32 + l*4];
        #pragma unroll
        for (int i = 0; i < 3; ++i) {
            float4 wv = wp[i][q];
            acc[i] += xr.x*wv.x + xr.y*wv.y + xr.z*wv.z + xr.w*wv.w;
        }
    }
    #pragma unroll
    for (int i = 0; i < 3; ++i) outT[l*97 + cg*3 + i] = acc[i];
    __syncthreads();
    // ---- coalesced write with residual ----
    #pragma unroll
    for (int it = 0; it < 3; ++it) {
        int idx = it*256 + tid;       // 768 outputs
        int p = idx / 96, cc = idx % 96;
        size_t o = (size_t)(b*L_ + l0 + p)*C_ + cc;
        out[o] = xin[o] + outT[p*97 + cc];
    }
}

extern "C" void kernel_launch(void* const* d_in, const int* in_sizes, int n_in,
                              void* d_out, int out_size, void* d_ws, size_t ws_size,
                              hipStream_t stream) {
    const float* x        = (const float*)d_in[0];
    const float* in_proj  = (const float*)d_in[1];
    const float* conv_w   = (const float*)d_in[2];
    const float* conv_b   = (const float*)d_in[3];
    const float* x_proj_w = (const float*)d_in[4];
    const float* dt_w     = (const float*)d_in[5];
    const float* dt_b     = (const float*)d_in[6];
    const float* A_logs   = (const float*)d_in[7];
    const float* Ds       = (const float*)d_in[8];
    const float* ln_w     = (const float*)d_in[9];
    const float* ln_b     = (const float*)d_in[10];
    const float* out_w    = (const float*)d_in[11];
    float* out = (float*)d_out;
    float* ws  = (float*)d_ws;

    k1_inproj <<<576,  256, 0, stream>>>(x, in_proj, ws);
    k2_conv   <<<768,  256, 0, stream>>>(conv_w, conv_b, ws);
    k3_xproj  <<<1152, 256, 0, stream>>>(x_proj_w, dt_w, dt_b, ws);
    k4a_local <<<768,  512, 0, stream>>>(A_logs, ws);
    k4c_scan  <<<768,  512, 0, stream>>>(A_logs, ws);
    k56_fused <<<576,  256, 0, stream>>>(ln_w, ln_b, Ds, out_w, x, out, ws);
}

// Round 20
// 251.539 us; speedup vs baseline: 1.1184x; 1.0029x over previous
//
#include <hip/hip_runtime.h>
#include <math.h>

#define B_ 2
#define H_ 48
#define W_ 48
#define C_ 96
#define D_ 192
#define L_ 2304   // H_*W_
#define K_ 4
#define NS 32     // D_STATE
#define RK 6      // DT_RANK
#define CD 70     // RK + 2*NS

#define NC 16         // scan chunks
#define CL (L_/NC)    // 144 steps per chunk
#define NCH (B_*K_*D_)// 1536 chains

// workspace offsets (floats)
#define BDL (B_*D_*L_)                    // 884736
#define OFF_Z      0                      // z stored (b, l, d)
#define OFF_XPRE   (OFF_Z    + BDL)
#define OFF_XHW    (OFF_XPRE + BDL)
#define OFF_XWH    (OFF_XHW  + BDL)
#define OFF_DELTA  (OFF_XWH  + BDL)      // size B*K*D*L, layout (b,k,d,l)
#define OFF_BS     (OFF_DELTA+ B_*K_*D_*L_)  // (b,k,l,n)
#define OFF_CS     (OFF_BS   + B_*K_*L_*NS)
#define OFF_YS     (OFF_CS   + B_*K_*L_*NS)  // blocked: [bk][c][dg][lc][32]
#define OFF_YF     (OFF_YS   + B_*K_*L_*D_)

// DU aliases the YS region: du layout [bk][c][d(192)][lc(144)].
#define OFF_DU     OFF_YS

// H0 scratch: NCH*NC*NS = 786432 floats in the YF region (separate from YS).
#define OFF_H0     OFF_YF

// raw v_exp_f32 (exp2); log2e folded into the per-lane A constant once.
__device__ __forceinline__ float fexp2(float x) {
    float r; asm("v_exp_f32 %0, %1" : "=v"(r) : "v"(x)); return r;
}

// ---------------- K1: in_proj GEMM ------------------------------------------
// grid 576 = b(2) * ltile32(72) * es(4); es 0,1 -> xpre (b,d,pos); 2,3 -> z (b,l,d)
// R18: stage the 96x96 es-slice of in_proj_w in LDS (36 KB, coalesced burst).
__global__ __launch_bounds__(256) void k1_inproj(const float* __restrict__ x,
        const float* __restrict__ w, float* __restrict__ ws) {
    __shared__ __align__(16) float Xs[24*128];   // [cq][l*4+sub], 32 l
    __shared__ __align__(16) float Wl[96*96];    // 36 KB staged weight slice
    int blk = blockIdx.x;
    int b = blk / 288;
    int rem = blk % 288;
    int l0 = (rem >> 2) * 32;
    int es = rem & 3;
    int tid = threadIdx.x;
    // ---- stage weights: rows es*96 .. es*96+95 (contiguous 9216 floats) ----
    const float4* wsrc = (const float4*)(w + (size_t)(es*96)*96);
    #pragma unroll
    for (int it = 0; it < 9; ++it) {
        int i4 = it*256 + tid;        // 2304 float4
        *(float4*)&Wl[i4*4] = wsrc[i4];
    }
    const float4* xs4 = (const float4*)(x + (size_t)(b*L_ + l0)*C_);
    #pragma unroll
    for (int it = 0; it < 3; ++it) {
        int i4 = it*256 + tid;        // 768 float4 = 3072 floats
        float4 v = xs4[i4];
        int idx4 = i4*4;
        int p = idx4 / 96, c = idx4 % 96;   // c % 4 == 0
        *(float4*)&Xs[(c>>2)*128 + p*4] = v;
    }
    __syncthreads();
    int l = tid & 31, eg = tid >> 5;
    int pos = l0 + l;
    float acc[12];
    #pragma unroll
    for (int i = 0; i < 12; ++i) acc[i] = 0.f;
    for (int q = 0; q < 24; ++q) {
        float4 xr = *(const float4*)&Xs[q*128 + l*4];
        #pragma unroll
        for (int i = 0; i < 12; ++i) {
            float4 wv = *(const float4*)&Wl[(eg*12 + i)*96 + q*4];
            acc[i] += xr.x*wv.x + xr.y*wv.y + xr.z*wv.z + xr.w*wv.w;
        }
    }
    if (es < 2) {
        float* xpre = ws + OFF_XPRE;
        #pragma unroll
        for (int i = 0; i < 12; ++i) {
            int e = es*96 + eg*12 + i;
            xpre[(size_t)(b*D_ + e)*L_ + pos] = acc[i];
        }
    } else {
        float* zp = ws + OFF_Z + (size_t)(b*L_ + pos)*D_ + (es-2)*96 + eg*12;
        #pragma unroll
        for (int q = 0; q < 3; ++q)
            *(float4*)&zp[q*4] = make_float4(acc[q*4], acc[q*4+1], acc[q*4+2], acc[q*4+3]);
    }
}

// ---------------- K2: depthwise 3x3 conv + SiLU, half-image blocks ----------
__global__ __launch_bounds__(256) void k2_conv(const float* __restrict__ cw,
        const float* __restrict__ cb, float* __restrict__ ws) {
    __shared__ float img[26*48];
    __shared__ float res[24*49];     // padded for transpose read
    int blk = blockIdx.x;            // 768 = bd*2 + half
    int bd = blk >> 1;
    int half = blk & 1;
    int d = bd % D_;
    int hh0 = half * 24;
    int tid = threadIdx.x;
    const float* xp = ws + OFF_XPRE + (size_t)bd*L_;
    for (int it = 0; it < 5; ++it) {
        int idx = it*256 + tid;
        if (idx < 26*48) {
            int gr = hh0 - 1 + idx/48;
            img[idx] = (gr >= 0 && gr < H_) ? xp[gr*48 + idx%48] : 0.f;
        }
    }
    float wr[9];
    #pragma unroll
    for (int j = 0; j < 9; ++j) wr[j] = cw[d*9 + j];
    float bias = cb[d];
    __syncthreads();
    float* hw = ws + OFF_XHW + (size_t)bd*L_ + hh0*48;
    for (int it = 0; it < 5; ++it) {
        int idx = it*256 + tid;
        if (idx < 24*48) {
            int r = idx/48, w0 = idx%48;
            float acc = bias;
            #pragma unroll
            for (int kh = 0; kh < 3; ++kh) {
                #pragma unroll
                for (int kw = 0; kw < 3; ++kw) {
                    int iw = w0 + kw - 1;
                    if (iw >= 0 && iw < W_)
                        acc = fmaf(img[(r+kh)*48 + iw], wr[kh*3 + kw], acc);
                }
            }
            float v = acc / (1.f + __expf(-acc));
            hw[idx] = v;
            res[r*49 + w0] = v;
        }
    }
    __syncthreads();
    float* wh = ws + OFF_XWH + (size_t)bd*L_;
    for (int it = 0; it < 5; ++it) {
        int idx = it*256 + tid;
        if (idx < 24*48) {
            int w0 = idx/24, r = idx%24;
            wh[w0*48 + hh0 + r] = res[r*49 + w0];
        }
    }
}

// ---------------- K3: x_proj matvec + dt_proj + softplus + B/C + du ---------
// grid 1152 = b(2) * k(4) * ltile16(144). Weights staged in LDS (R17).
__global__ __launch_bounds__(256) void k3_xproj(const float* __restrict__ xpw,
        const float* __restrict__ dtw, const float* __restrict__ dtb,
        float* __restrict__ ws) {
    __shared__ __align__(16) float Xs[48*64];    // [dq][l*4+sub], 16 l
    __shared__ float xd[CD*17];                  // [c][l], pad 17
    __shared__ __align__(16) float Wl[CD*196];   // 54.9 KB staged weights
    int blk = blockIdx.x;
    int b = blk / 576;
    int rem = blk % 576;
    int k = rem / 144;
    int l0 = (rem % 144) * 16;
    int tid = threadIdx.x;
    // ---- stage weights: CD*48 = 3360 float4, coalesced ----
    const float4* wsrc = (const float4*)(xpw + (size_t)k*CD*D_);
    #pragma unroll
    for (int it = 0; it < 14; ++it) {
        int i4 = it*256 + tid;
        if (i4 < CD*48) {
            int c = i4 / 48, q = i4 % 48;
            float4 v = wsrc[i4];
            *(float4*)&Wl[c*196 + q*4] = v;
        }
    }
    const float* src = ws + ((k & 1) ? OFF_XWH : OFF_XHW);
    bool flip = (k >= 2);
    #pragma unroll
    for (int it = 0; it < 12; ++it) {
        int idx = it*256 + tid;
        int d = idx >> 4, l = idx & 15;
        int pos = flip ? (L_ - 1 - (l0 + l)) : (l0 + l);
        Xs[(d>>2)*64 + l*4 + (d&3)] = src[(size_t)(b*D_ + d)*L_ + pos];
    }
    __syncthreads();
    int l = tid & 15, cg = tid >> 4;    // 16 l x 16 cg
    {
        float acc[5] = {0.f, 0.f, 0.f, 0.f, 0.f};
        int cr[5];
        #pragma unroll
        for (int i = 0; i < 5; ++i) {
            int c = cg + 16*i;
            if (c >= CD) c = 0;          // guard OOB; result masked on write
            cr[i] = c*196;
        }
        for (int q = 0; q < 48; ++q) {
            float4 xr = *(const float4*)&Xs[q*64 + l*4];
            #pragma unroll
            for (int i = 0; i < 5; ++i) {
                float4 wv = *(const float4*)&Wl[cr[i] + q*4];
                acc[i] += xr.x*wv.x + xr.y*wv.y + xr.z*wv.z + xr.w*wv.w;
            }
        }
        #pragma unroll
        for (int i = 0; i < 5; ++i) {
            int c = cg + 16*i;
            if (c < CD) xd[c*17 + l] = acc[i];
        }
    }
    __syncthreads();
    {   // dt_proj + softplus -> deltas (b,k,d,l) AND du (blocked scan layout)
        float r[6];
        #pragma unroll
        for (int rr = 0; rr < 6; ++rr) r[rr] = xd[rr*17 + l];
        int bk = b*K_ + k;
        float* dout = ws + OFF_DELTA + (size_t)bk*D_*L_;
        int cch = l0 / CL;               // tiles of 16 never straddle CL=144
        int lc  = l0 - cch*CL + l;
        float* dup = ws + OFF_DU + ((size_t)(bk*NC + cch))*D_*CL;
        int dg = tid >> 4;
        for (int i = 0; i < 12; ++i) {
            int d = dg*12 + i;
            const float* wdt = dtw + ((size_t)k*D_ + d)*6;
            float acc = dtb[k*D_ + d];
            #pragma unroll
            for (int rr = 0; rr < 6; ++rr) acc = fmaf(r[rr], wdt[rr], acc);
            float sp = fmaxf(acc, 0.f) + log1pf(__expf(-fabsf(acc)));
            dout[(size_t)d*L_ + l0 + l] = sp;
            float uv = Xs[(d>>2)*64 + l*4 + (d&3)];   // u in scan order
            dup[(size_t)d*CL + lc] = sp * uv;
        }
    }
    {   // Bs/Cs -> (b,k,l,n)
        float* Bsp = ws + OFF_BS + ((size_t)(b*K_ + k)*L_ + l0)*NS;
        float* Csp = ws + OFF_CS + ((size_t)(b*K_ + k)*L_ + l0)*NS;
        int n = tid & 31, lq = tid >> 5;
        #pragma unroll
        for (int j = 0; j < 2; ++j) {
            int ll = lq + 8*j;
            Bsp[(size_t)ll*NS + n] = xd[(RK + n)*17 + ll];
            Csp[(size_t)ll*NS + n] = xd[(RK + NS + n)*17 + ll];
        }
    }
}

// ---------------- K4a: local chunk scan + in-LDS combine -> H0 --------------
// block = (bk, d-pair); 512 threads = 16 chunks x 32 states; 2 chains/lane.
// Double-buffered register prefetch (R14 mechanism, measured-passing twice).
__global__ __launch_bounds__(512) void k4a_local(const float* __restrict__ Alogs,
        float* __restrict__ ws) {
    __shared__ float Pl[2][NC][NS];
    __shared__ float Hl[2][NC][NS];
    int blk = blockIdx.x;            // 768 = bk(8) * pair(96)
    int bk = blk / 96;
    int p = blk % 96;
    int k = bk & 3;
    int c = threadIdx.x >> 5;
    int n = threadIdx.x & 31;
    int dA = 2*p;
    float aA2 = -__expf(Alogs[((size_t)k*D_ + dA)*NS + n]) * 1.44269504f;
    float aB2 = -__expf(Alogs[((size_t)k*D_ + dA + 1)*NS + n]) * 1.44269504f;
    const float* dpA = ws + OFF_DELTA + (size_t)(bk*D_ + dA)*L_ + c*CL;
    const float* dpB = dpA + L_;
    const float* duA = ws + OFF_DU + ((size_t)(bk*NC + c)*D_ + dA)*CL;
    const float* duB = duA + CL;
    const float* Bsp = ws + OFF_BS + ((size_t)bk*L_ + c*CL)*NS;
    float hA = 0.f, hB = 0.f, PA = 1.f, PB = 1.f;

    float XdA[4], XdB[4], XuA[4], XuB[4], Xbn[4];
    float YdA[4], YdB[4], YuA[4], YuB[4], Ybn[4];
#define KL4(Pr, base) { \
    _Pragma("unroll") \
    for (int j = 0; j < 4; ++j) { \
        int l_ = (base) + j; \
        Pr##dA[j] = dpA[l_]; Pr##dB[j] = dpB[l_]; \
        Pr##uA[j] = duA[l_]; Pr##uB[j] = duB[l_]; \
        Pr##bn[j] = Bsp[l_*NS + n]; \
    } }
#define KC4(Pr) { \
    _Pragma("unroll") \
    for (int j = 0; j < 4; ++j) { \
        float eA = fexp2(Pr##dA[j] * aA2); \
        float eB = fexp2(Pr##dB[j] * aB2); \
        hA = fmaf(hA, eA, Pr##uA[j]*Pr##bn[j]); \
        hB = fmaf(hB, eB, Pr##uB[j]*Pr##bn[j]); \
        PA *= eA; \
        PB *= eB; \
    } }
    KL4(X, 0);
    for (int lb = 0; lb < CL; lb += 8) {
        KL4(Y, lb+4);
        KC4(X);
        if (lb + 8 < CL) KL4(X, lb+8);
        KC4(Y);
    }
#undef KL4
#undef KC4
    Pl[0][c][n] = PA; Pl[1][c][n] = PB;
    Hl[0][c][n] = hA; Hl[1][c][n] = hB;
    __syncthreads();
    if (threadIdx.x < 64) {
        int ch = threadIdx.x >> 5, nn = threadIdx.x & 31;
        float* H0p = ws + OFF_H0 + (size_t)(bk*D_ + dA + ch)*NC*NS + nn;
        float h = 0.f;
        #pragma unroll
        for (int cc = 0; cc < NC; ++cc) {
            H0p[cc*NS] = h;
            h = fmaf(h, Pl[ch][cc][nn], Hl[ch][cc][nn]);
        }
    }
}

// ---------------- K4c: replay with true h0; y staged in LDS ----------------
// block = (bk, chunk, 32-d group); 512 threads = 16 subwaves x 2 chains.
// Double-buffered register prefetch (R14 mechanism, measured-passing twice).
__global__ __launch_bounds__(512) void k4c_scan(const float* __restrict__ Alogs,
        float* __restrict__ ws) {
    __shared__ float yld[CL*32];     // [l][dd] 18.4KB
    int blk = blockIdx.x;            // 768 = bk(8) * c(16) * dg(6)
    int dg = blk % 6;
    int c  = (blk / 6) % NC;
    int bk = blk / (6*NC);
    int k = bk & 3;
    int sw = threadIdx.x >> 5;
    int n  = threadIdx.x & 31;
    int dA = dg*32 + sw;
    int dB = dA + 16;
    float aA2 = -__expf(Alogs[((size_t)k*D_ + dA)*NS + n]) * 1.44269504f;
    float aB2 = -__expf(Alogs[((size_t)k*D_ + dB)*NS + n]) * 1.44269504f;
    const float* dpA = ws + OFF_DELTA + (size_t)(bk*D_ + dA)*L_ + c*CL;
    const float* dpB = dpA + 16*L_;
    const float* duA = ws + OFF_DU + ((size_t)(bk*NC + c)*D_ + dA)*CL;
    const float* duB = duA + 16*CL;
    const float* Bsp = ws + OFF_BS + ((size_t)bk*L_ + c*CL)*NS;
    const float* Csp = ws + OFF_CS + ((size_t)bk*L_ + c*CL)*NS;
    float hA = ws[OFF_H0 + (size_t)(bk*D_ + dA)*NC*NS + c*NS + n];
    float hB = ws[OFF_H0 + (size_t)(bk*D_ + dB)*NC*NS + c*NS + n];
    int g = n >> 3;
    int off = ((g & 1) << 1) | (g >> 1);

    float XdA[4], XdB[4], XuA[4], XuB[4], Xbn[4], Xcn[4];
    float YdA[4], YdB[4], YuA[4], YuB[4], Ybn[4], Ycn[4];
#define CL4(Pr, base) { \
    _Pragma("unroll") \
    for (int j = 0; j < 4; ++j) { \
        int l_ = (base) + j; \
        Pr##dA[j] = dpA[l_]; Pr##dB[j] = dpB[l_]; \
        Pr##uA[j] = duA[l_]; Pr##uB[j] = duB[l_]; \
        Pr##bn[j] = Bsp[l_*NS + n]; \
        Pr##cn[j] = Csp[l_*NS + n]; \
    } }
#define CC4(Pr, lbase) { \
    float yA[4], yB[4]; \
    _Pragma("unroll") \
    for (int j = 0; j < 4; ++j) { \
        hA = fmaf(hA, fexp2(Pr##dA[j]*aA2), Pr##uA[j]*Pr##bn[j]); \
        hB = fmaf(hB, fexp2(Pr##dB[j]*aB2), Pr##uB[j]*Pr##bn[j]); \
        yA[j] = hA * Pr##cn[j]; yB[j] = hB * Pr##cn[j]; \
    } \
    _Pragma("unroll") \
    for (int j = 0; j < 4; ++j) { \
        yA[j] += __shfl_xor(yA[j], 16); \
        yB[j] += __shfl_xor(yB[j], 16); \
    } \
    float zA0 = (n & 16) ? yA[1] : yA[0]; \
    float zA1 = (n & 16) ? yA[3] : yA[2]; \
    float zB0 = (n & 16) ? yB[1] : yB[0]; \
    float zB1 = (n & 16) ? yB[3] : yB[2]; \
    zA0 += __shfl_xor(zA0, 8); zA1 += __shfl_xor(zA1, 8); \
    zB0 += __shfl_xor(zB0, 8); zB1 += __shfl_xor(zB1, 8); \
    float wA = (n & 8) ? zA1 : zA0; \
    float wB = (n & 8) ? zB1 : zB0; \
    wA += __shfl_xor(wA, 4); wA += __shfl_xor(wA, 2); wA += __shfl_xor(wA, 1); \
    wB += __shfl_xor(wB, 4); wB += __shfl_xor(wB, 2); wB += __shfl_xor(wB, 1); \
    if ((n & 7) == 0) { \
        yld[((lbase) + off)*32 + sw]      = wA; \
        yld[((lbase) + off)*32 + sw + 16] = wB; \
    } }
    CL4(X, 0);
    for (int lb = 0; lb < CL; lb += 8) {
        CL4(Y, lb+4);
        CC4(X, lb);
        if (lb + 8 < CL) CL4(X, lb+8);
        CC4(Y, lb+4);
    }
#undef CL4
#undef CC4
    __syncthreads();
    // blk == (bk*NC + c)*6 + dg, so the YS cell is exactly the du cell read
    float* ysp = ws + OFF_YS + (size_t)blk*(CL*32);
    #pragma unroll
    for (int it = 0; it < 9; ++it) {
        int idx = it*512 + threadIdx.x;
        ysp[idx] = yld[idx];
    }
}

// ---------------- K56: merge 4 dirs + D-term + LN + SiLU(z) + out_proj + res
// R19: grid 288 = b(2) * ltile16(144); 512 threads; out_proj weights staged
// in LDS (75 KB, stride 196 for bank spread) — third instance of the proven
// weight-staging mechanism. ~99 KB LDS -> 1 block/CU (288 blocks ~= 256 CUs).
__global__ __launch_bounds__(512) void k56_fused(const float* __restrict__ lnw,
        const float* __restrict__ lnb, const float* __restrict__ dsp,
        const float* __restrict__ w, const float* __restrict__ xin,
        float* __restrict__ out, const float* __restrict__ ws) {
    __shared__ __align__(16) float Ys[48*64];    // [dq][p*4+sub], 16 p
    __shared__ __align__(16) float Wl[96*196];   // 75.3 KB staged out_proj
    __shared__ float redS[16][33];
    __shared__ float redQ[16][33];
    __shared__ float muS[16], rsS[16];
    __shared__ float Dsum[D_];
    __shared__ float outT[16*97];
    int blk = blockIdx.x;
    int b = blk / 144;
    int l0 = (blk % 144) * 16;
    int tid = threadIdx.x;
    int hh = l0 / W_;       // 16-tiles stay within one row (48/16 = 3/row)
    int w0b = l0 % W_;
    if (tid < D_) Dsum[tid] = dsp[tid] + dsp[D_+tid] + dsp[2*D_+tid] + dsp[3*D_+tid];
    // ---- stage out_proj weights: 96x192 = 4608 float4, coalesced ----
    const float4* wsrc4 = (const float4*)w;
    #pragma unroll
    for (int it = 0; it < 9; ++it) {
        int i4 = it*512 + tid;
        if (i4 < 96*48) {
            int c = i4 / 48, q = i4 % 48;
            *(float4*)&Wl[c*196 + q*4] = wsrc4[i4];
        }
    }
    const float* ysb = ws + OFF_YS;
    int bk0 = b*K_;
    // ---- stage merged 4-direction y into GEMM layout (blocked YS reads) ----
    #pragma unroll
    for (int it = 0; it < 2; ++it) {
        int i4 = it*512 + tid;        // 768 float4 (16 pos x 48 quads)
        if (i4 < 768) {
            int p = i4 / 48, c48 = i4 % 48;
            int pos    = l0 + p;
            int posr   = L_ - 1 - pos;
            int poswh  = (w0b + p)*H_ + hh;
            int poswhr = L_ - 1 - poswh;
            int dsub = c48 >> 3;          // dg
            int doff = (c48 & 7) * 4;     // d' within 32-group
            float4 a  = *(const float4*)&ysb[((((size_t)(bk0+0)*NC + pos   /CL)*6 + dsub)*CL + pos   %CL)*32 + doff];
            float4 bb = *(const float4*)&ysb[((((size_t)(bk0+2)*NC + posr  /CL)*6 + dsub)*CL + posr  %CL)*32 + doff];
            float4 cc = *(const float4*)&ysb[((((size_t)(bk0+1)*NC + poswh /CL)*6 + dsub)*CL + poswh %CL)*32 + doff];
            float4 dd = *(const float4*)&ysb[((((size_t)(bk0+3)*NC + poswhr/CL)*6 + dsub)*CL + poswhr%CL)*32 + doff];
            float4 v = make_float4(a.x+bb.x+cc.x+dd.x, a.y+bb.y+cc.y+dd.y,
                                   a.z+bb.z+cc.z+dd.z, a.w+bb.w+cc.w+dd.w);
            *(float4*)&Ys[c48*64 + p*4] = v;
        }
    }
    __syncthreads();
    // ---- add Dsum_d * xhw[b,d,pos] (the folded Ds*u term, pre-LN) ----
    const float* xhw = ws + OFF_XHW;
    #pragma unroll
    for (int it = 0; it < 6; ++it) {
        int idx = it*512 + tid;       // 3072 = d(192) x p(16)
        int d = idx >> 4, p = idx & 15;
        float xv = xhw[(size_t)(b*D_ + d)*L_ + l0 + p];
        Ys[(d>>2)*64 + p*4 + (d&3)] += Dsum[d]*xv;
    }
    __syncthreads();
    // ---- per-position LN partial sums: 32 groups per position ----
    {
        int p = tid & 15, g = tid >> 4;  // g in [0,32)
        float s = 0.f, q = 0.f;
        {   // quad g
            #pragma unroll
            for (int sx = 0; sx < 4; ++sx) {
                float v = Ys[g*64 + p*4 + sx];
                s += v; q += v*v;
            }
        }
        if (g < 16) {   // quad g+32
            #pragma unroll
            for (int sx = 0; sx < 4; ++sx) {
                float v = Ys[(g+32)*64 + p*4 + sx];
                s += v; q += v*v;
            }
        }
        redS[p][g] = s; redQ[p][g] = q;
    }
    __syncthreads();
    if (tid < 16) {
        float s = 0.f, q = 0.f;
        #pragma unroll
        for (int g = 0; g < 32; ++g) { s += redS[tid][g]; q += redQ[tid][g]; }
        float mu  = s * (1.f/192.f);
        float var = q * (1.f/192.f) - mu*mu;
        muS[tid] = mu;
        rsS[tid] = rsqrtf(var + 1e-5f);
    }
    __syncthreads();
    // ---- LN + SiLU(z) gate, in place ----
    #pragma unroll
    for (int it = 0; it < 2; ++it) {
        int i4 = it*512 + tid;
        if (i4 < 768) {
            int p = i4 / 48, c48 = i4 % 48;
            int pos = l0 + p;
            float4 v  = *(float4*)&Ys[c48*64 + p*4];
            float4 wv = *(const float4*)(lnw + c48*4);
            float4 bv = *(const float4*)(lnb + c48*4);
            float4 zv = *(const float4*)(ws + OFF_Z + (size_t)(b*L_ + pos)*D_ + c48*4);
            float mu = muS[p], rs = rsS[p];
            float o0 = ((v.x-mu)*rs*wv.x + bv.x) * (zv.x / (1.f + __expf(-zv.x)));
            float o1 = ((v.y-mu)*rs*wv.y + bv.y) * (zv.y / (1.f + __expf(-zv.y)));
            float o2 = ((v.z-mu)*rs*wv.z + bv.z) * (zv.z / (1.f + __expf(-zv.z)));
            float o3 = ((v.w-mu)*rs*wv.w + bv.w) * (zv.w / (1.f + __expf(-zv.w)));
            *(float4*)&Ys[c48*64 + p*4] = make_float4(o0, o1, o2, o3);
        }
    }
    __syncthreads();
    // ---- out_proj GEMM: 16 l x 32 cg, 3 outputs/thread (96 channels) ----
    int l = tid & 15, cg = tid >> 4;
    float acc[3] = {0.f, 0.f, 0.f};
    for (int q = 0; q < 48; ++q) {
        float4 xr = *(const float4*)&Ys[q*64 + l*4];
        #pragma unroll
        for (int i = 0; i < 3; ++i) {
            float4 wv = *(const float4*)&Wl[(cg*3 + i)*196 + q*4];
            acc[i] += xr.x*wv.x + xr.y*wv.y + xr.z*wv.z + xr.w*wv.w;
        }
    }
    #pragma unroll
    for (int i = 0; i < 3; ++i) outT[l*97 + cg*3 + i] = acc[i];
    __syncthreads();
    // ---- coalesced write with residual ----
    #pragma unroll
    for (int it = 0; it < 3; ++it) {
        int idx = it*512 + tid;       // 1536 outputs
        int p = idx / 96, cc = idx % 96;
        size_t o = (size_t)(b*L_ + l0 + p)*C_ + cc;
        out[o] = xin[o] + outT[p*97 + cc];
    }
}

extern "C" void kernel_launch(void* const* d_in, const int* in_sizes, int n_in,
                              void* d_out, int out_size, void* d_ws, size_t ws_size,
                              hipStream_t stream) {
    const float* x        = (const float*)d_in[0];
    const float* in_proj  = (const float*)d_in[1];
    const float* conv_w   = (const float*)d_in[2];
    const float* conv_b   = (const float*)d_in[3];
    const float* x_proj_w = (const float*)d_in[4];
    const float* dt_w     = (const float*)d_in[5];
    const float* dt_b     = (const float*)d_in[6];
    const float* A_logs   = (const float*)d_in[7];
    const float* Ds       = (const float*)d_in[8];
    const float* ln_w     = (const float*)d_in[9];
    const float* ln_b     = (const float*)d_in[10];
    const float* out_w    = (const float*)d_in[11];
    float* out = (float*)d_out;
    float* ws  = (float*)d_ws;

    k1_inproj <<<576,  256, 0, stream>>>(x, in_proj, ws);
    k2_conv   <<<768,  256, 0, stream>>>(conv_w, conv_b, ws);
    k3_xproj  <<<1152, 256, 0, stream>>>(x_proj_w, dt_w, dt_b, ws);
    k4a_local <<<768,  512, 0, stream>>>(A_logs, ws);
    k4c_scan  <<<768,  512, 0, stream>>>(A_logs, ws);
    k56_fused <<<288,  512, 0, stream>>>(ln_w, ln_b, Ds, out_w, x, out, ws);
}